// Round 9
// baseline (209.628 us; speedup 1.0000x reference)
//
#include <hip/hip_runtime.h>
#include <stdint.h>

// MultiHeadAttention: B=4, S=2048, D_MODEL=1024, H=16, d_k=d_v=64
// Round 9: QKV GEMM -> 256^2 counted-vmcnt structure (T3+T4): 8 waves,
// BK=64, 128KiB dbuf LDS, raw s_barrier + s_waitcnt vmcnt(8) (never 0
// mid-loop), 2-deep prefetch, A-frag reuse, setprio. Attn & rest = round 8.

typedef __bf16 bf16;
typedef __bf16 bf16x8 __attribute__((ext_vector_type(8)));
typedef __bf16 bf16x4 __attribute__((ext_vector_type(4)));
typedef float f32x4 __attribute__((ext_vector_type(4)));
typedef float f32x16 __attribute__((ext_vector_type(16)));

#define DM    1024
#define NH    16
#define SS    2048
#define BB    4
#define NTOK  8192
#define QKVLD 3072
#define LOG2E_DIV8 0.18033688011112042f   // log2(e)/8: scale folded into Q, exp2 domain
#define CSHIFT 12.0f                      // fixed softmax shift (folded into bias)

__device__ __forceinline__ int swz(int row, int byteoff) {
    return byteoff ^ ((row & 7) << 4);
}
__device__ __forceinline__ float fexp2(float x) {
    float r; asm("v_exp_f32 %0, %1" : "=v"(r) : "v"(x)); return r;
}
__device__ __forceinline__ uint32_t cvtpk(float lo, float hi_) {
    uint32_t r; asm("v_cvt_pk_bf16_f32 %0, %1, %2" : "=v"(r) : "v"(lo), "v"(hi_)); return r;
}
__device__ __forceinline__ void gload_lds16(const void* g, void* l) {
    __builtin_amdgcn_global_load_lds(
        (const __attribute__((address_space(1))) uint32_t*)g,
        (__attribute__((address_space(3))) uint32_t*)l, 16, 0, 0);
}

__global__ void cvt_kernel(const float* __restrict__ in, bf16* __restrict__ out, int n8) {
    int i = blockIdx.x * blockDim.x + threadIdx.x;
    if (i >= n8) return;
    const float4* p = reinterpret_cast<const float4*>(in) + (size_t)i * 2;
    float4 a = p[0], b = p[1];
    bf16x8 o;
    o[0] = (bf16)a.x; o[1] = (bf16)a.y; o[2] = (bf16)a.z; o[3] = (bf16)a.w;
    o[4] = (bf16)b.x; o[5] = (bf16)b.y; o[6] = (bf16)b.z; o[7] = (bf16)b.w;
    reinterpret_cast<bf16x8*>(out)[i] = o;
}

// all 4 weight matrices (1M fp32 each) in one launch
__global__ void wcvt_kernel(const float* __restrict__ wq, const float* __restrict__ wk,
                            const float* __restrict__ wv, const float* __restrict__ wo,
                            bf16* __restrict__ wqkv, bf16* __restrict__ wob) {
    int i = blockIdx.x * blockDim.x + threadIdx.x;   // 8-elem group id, 4*131072 total
    int seg = i >> 17, off = i & 131071;
    const float* src = (seg == 0) ? wq : (seg == 1) ? wk : (seg == 2) ? wv : wo;
    bf16* dst = (seg < 3) ? (wqkv + (size_t)seg * DM * DM) : wob;
    const float4* p = reinterpret_cast<const float4*>(src) + (size_t)off * 2;
    float4 a = p[0], b = p[1];
    bf16x8 o;
    o[0] = (bf16)a.x; o[1] = (bf16)a.y; o[2] = (bf16)a.z; o[3] = (bf16)a.w;
    o[4] = (bf16)b.x; o[5] = (bf16)b.y; o[6] = (bf16)b.z; o[7] = (bf16)b.w;
    reinterpret_cast<bf16x8*>(dst)[off] = o;
}

// bias[b4][kt16][kg4][hi2][e16]: -inf where key padded, else -CSHIFT.
__global__ void biasprep_kernel(const int* __restrict__ mask, float* __restrict__ bias) {
    int idx = blockIdx.x * blockDim.x + threadIdx.x;
    if (idx >= 4 * 2048) return;
    int e = idx & 15, hi = (idx >> 4) & 1, kg = (idx >> 5) & 3;
    int kt = (idx >> 7) & 15, b = idx >> 11;
    int key = kt * 128 + kg * 32 + 4 * hi + 8 * (e >> 2) + (e & 3);
    bias[idx] = mask[b * SS + key] ? -__builtin_inff() : -CSHIFT;
}

// ---------------- 256^2 counted-vmcnt GEMM (QKV projection) ----------------
// C[M,N] = A[M,K](lda) * Bm[N,K]^T, bf16 out. 8 waves (2M x 4N), BK=64,
// LDS 128KiB: [buf][half] 128x64 tiles for A and B. Raw barriers, vmcnt(8).
__global__ __launch_bounds__(512, 2) void gemm_bt256(
    const bf16* __restrict__ A, int lda, const bf16* __restrict__ Bm,
    bf16* __restrict__ C, int M, int N, int K)
{
    __shared__ bf16 As[2][2][128 * 64];   // 64 KiB
    __shared__ bf16 Bs[2][2][128 * 64];   // 64 KiB

    const int nwg = gridDim.x * gridDim.y;
    const int wg = blockIdx.y * gridDim.x + blockIdx.x;
    const int nsw = (wg & 7) * (nwg >> 3) + (wg >> 3);
    const int tn = nsw % gridDim.x, tm = nsw / gridDim.x;

    const int tid = threadIdx.x;
    const int lane = tid & 63, wv = tid >> 6;
    const int wm = wv >> 2, wn = wv & 3;         // 2 x 4 wave grid
    const int lr = lane & 15, lg = lane >> 4;

    f32x4 acc[8][4];
#pragma unroll
    for (int mi = 0; mi < 8; ++mi)
#pragma unroll
        for (int ni = 0; ni < 4; ++ni) {
            f32x4 z = {0.f, 0.f, 0.f, 0.f};
            acc[mi][ni] = z;
        }

    // staging geometry: half-tile = 1024 x 16B chunks; thread does idx=tid, tid+512
    const int r0 = tid >> 3, c0 = tid & 7;
    const int r1 = (tid + 512) >> 3, c1 = tid & 7;
    const int g0 = (c0 * 16) ^ ((r0 & 7) << 4);
    const int g1 = (c1 * 16) ^ ((r1 & 7) << 4);
    const char* Ab = (const char*)(A + (size_t)(tm * 256) * lda);
    const char* Bb = (const char*)(Bm + (size_t)(tn * 256) * K);
    const size_t ldaB = (size_t)lda * 2, ldbB = (size_t)K * 2;

    auto stage = [&](int t) {   // 8 gload_lds per thread -> buf t&1
        const int buf = t & 1;
        const size_t kb = (size_t)t * 128;   // 64 elems * 2B
#pragma unroll
        for (int h = 0; h < 2; ++h) {
            gload_lds16(Ab + (size_t)(h * 128 + r0) * ldaB + kb + g0, (char*)As[buf][h] + tid * 16);
            gload_lds16(Ab + (size_t)(h * 128 + r1) * ldaB + kb + g1, (char*)As[buf][h] + (tid + 512) * 16);
            gload_lds16(Bb + (size_t)(h * 128 + r0) * ldbB + kb + g0, (char*)Bs[buf][h] + tid * 16);
            gload_lds16(Bb + (size_t)(h * 128 + r1) * ldbB + kb + g1, (char*)Bs[buf][h] + (tid + 512) * 16);
        }
    };

    const int nkt = K >> 6;      // 16 for K=1024
    stage(0);
    stage(1);

    for (int t = 0; t < nkt; ++t) {
        const int buf = t & 1;
        // counted vmcnt: oldest 8 outstanding = tile t's loads. Never 0 mid-loop.
        if (t + 1 < nkt) asm volatile("s_waitcnt vmcnt(8)" ::: "memory");
        else             asm volatile("s_waitcnt vmcnt(0)" ::: "memory");
        __builtin_amdgcn_s_barrier();    // raw barrier: no vmcnt(0) drain

        const char* Ah = (const char*)As[buf][wm];        // wave's A half
        const char* Bh = (const char*)Bs[buf][wn >> 1];   // wave's B half
        const int bbase = (wn & 1) * 64;

#pragma unroll
        for (int mh = 0; mh < 2; ++mh) {
            bf16x8 af[4][2];
#pragma unroll
            for (int mi = 0; mi < 4; ++mi) {
                int row = (mh * 4 + mi) * 16 + lr;
#pragma unroll
                for (int ks = 0; ks < 2; ++ks)
                    af[mi][ks] = *reinterpret_cast<const bf16x8*>(
                        Ah + swz(row, row * 128 + ks * 64 + lg * 16));
            }
#pragma unroll
            for (int nh = 0; nh < 2; ++nh) {
                __builtin_amdgcn_s_setprio(1);
#pragma unroll
                for (int ni = 0; ni < 2; ++ni) {
                    int row = bbase + (nh * 2 + ni) * 16 + lr;
                    bf16x8 b0 = *reinterpret_cast<const bf16x8*>(
                        Bh + swz(row, row * 128 + lg * 16));
                    bf16x8 b1 = *reinterpret_cast<const bf16x8*>(
                        Bh + swz(row, row * 128 + 64 + lg * 16));
#pragma unroll
                    for (int mi = 0; mi < 4; ++mi) {
                        acc[mh * 4 + mi][nh * 2 + ni] = __builtin_amdgcn_mfma_f32_16x16x32_bf16(
                            af[mi][0], b0, acc[mh * 4 + mi][nh * 2 + ni], 0, 0, 0);
                        acc[mh * 4 + mi][nh * 2 + ni] = __builtin_amdgcn_mfma_f32_16x16x32_bf16(
                            af[mi][1], b1, acc[mh * 4 + mi][nh * 2 + ni], 0, 0, 0);
                    }
                }
                __builtin_amdgcn_s_setprio(0);
            }
        }
        __builtin_amdgcn_s_barrier();    // all waves done reading buf
        if (t + 2 < nkt) stage(t + 2);   // safe: overwrites buf after barrier
    }

#pragma unroll
    for (int mi = 0; mi < 8; ++mi)
#pragma unroll
        for (int ni = 0; ni < 4; ++ni)
#pragma unroll
            for (int r = 0; r < 4; ++r) {
                int row = tm * 256 + wm * 128 + mi * 16 + lg * 4 + r;
                int col = tn * 256 + wn * 64 + ni * 16 + lr;
                C[(size_t)row * N + col] = (bf16)acc[mi][ni][r];
            }
}

// ---------------- 128^2 GEMM (output projection) ----------------
template <typename OT>
__global__ __launch_bounds__(256) void gemm_bt(
    const bf16* __restrict__ A, int lda, const bf16* __restrict__ Bm, OT* __restrict__ C,
    int M, int N, int K)
{
    __shared__ bf16 As[128 * 64];
    __shared__ bf16 Bs[128 * 64];

    const int nwg = gridDim.x * gridDim.y;
    const int wg = blockIdx.y * gridDim.x + blockIdx.x;
    const int nsw = (wg & 7) * (nwg >> 3) + (wg >> 3);
    const int tn = nsw % gridDim.x, tm = nsw / gridDim.x;

    const int tid = threadIdx.x;
    const int lane = tid & 63, wv = tid >> 6;
    const int wr = wv >> 1, wc = wv & 1;
    const int lr = lane & 15, lg = lane >> 4;

    const f32x4 zero = {0.f, 0.f, 0.f, 0.f};
    f32x4 acc[4][4];
#pragma unroll
    for (int mi = 0; mi < 4; ++mi)
#pragma unroll
        for (int ni = 0; ni < 4; ++ni) acc[mi][ni] = zero;

    const char* Abase = (const char*)(A + (size_t)(tm * 128) * lda);
    const char* Bbase = (const char*)(Bm + (size_t)(tn * 128) * K);

    for (int k0 = 0; k0 < K; k0 += 64) {
#pragma unroll
        for (int i = 0; i < 4; ++i) {
            int idx = tid + 256 * i;
            int row = idx >> 3, ch = idx & 7;
            int gcol = (ch * 16) ^ ((row & 7) << 4);
            gload_lds16(Abase + (size_t)row * (lda * 2) + k0 * 2 + gcol, (char*)As + idx * 16);
            gload_lds16(Bbase + (size_t)row * (K * 2) + k0 * 2 + gcol, (char*)Bs + idx * 16);
        }
        __syncthreads();

#pragma unroll
        for (int ks = 0; ks < 2; ++ks) {
            bf16x8 af[4], bfr[4];
#pragma unroll
            for (int mi = 0; mi < 4; ++mi) {
                int row = wr * 64 + mi * 16 + lr;
                af[mi] = *reinterpret_cast<const bf16x8*>(
                    (char*)As + swz(row, row * 128 + ks * 64 + lg * 16));
            }
#pragma unroll
            for (int ni = 0; ni < 4; ++ni) {
                int row = wc * 64 + ni * 16 + lr;
                bfr[ni] = *reinterpret_cast<const bf16x8*>(
                    (char*)Bs + swz(row, row * 128 + ks * 64 + lg * 16));
            }
#pragma unroll
            for (int mi = 0; mi < 4; ++mi)
#pragma unroll
                for (int ni = 0; ni < 4; ++ni)
                    acc[mi][ni] = __builtin_amdgcn_mfma_f32_16x16x32_bf16(
                        af[mi], bfr[ni], acc[mi][ni], 0, 0, 0);
        }
        __syncthreads();
    }

#pragma unroll
    for (int mi = 0; mi < 4; ++mi)
#pragma unroll
        for (int ni = 0; ni < 4; ++ni)
#pragma unroll
            for (int r = 0; r < 4; ++r) {
                int row = tm * 128 + wr * 64 + mi * 16 + lg * 4 + r;
                int col = tn * 128 + wc * 64 + ni * 16 + lr;
                C[(size_t)row * N + col] = (OT)acc[mi][ni][r];
            }
}

// Transpose V: vb[token][ldv] head-cols -> vT[(bh*64+d)][s]
__global__ __launch_bounds__(256) void vtrans_kernel(
    const bf16* __restrict__ vb, int ldv, bf16* __restrict__ vT)
{
    const int st = blockIdx.x, bh = blockIdx.y;
    const int b = bh >> 4, h = bh & 15;
    const int tid = threadIdx.x;
    __shared__ bf16 T[64 * 64];
#pragma unroll
    for (int i = 0; i < 2; ++i) {
        int idx = tid + 256 * i;
        int s = idx >> 3, ch = idx & 7;
        bf16x8 v = *reinterpret_cast<const bf16x8*>(
            vb + (size_t)(b * SS + st * 64 + s) * ldv + h * 64 + ch * 8);
        *reinterpret_cast<bf16x8*>((char*)T + swz(s, s * 128 + ch * 16)) = v;
    }
    __syncthreads();
#pragma unroll
    for (int i = 0; i < 2; ++i) {
        int idx = tid + 256 * i;
        int d = idx >> 3, ch = idx & 7;
        bf16x8 o;
#pragma unroll
        for (int j = 0; j < 8; ++j) {
            int s = ch * 8 + j;
            o[j] = *reinterpret_cast<const bf16*>((char*)T + swz(s, s * 128 + d * 2));
        }
        *reinterpret_cast<bf16x8*>(vT + ((size_t)bh * 64 + d) * SS + st * 64 + ch * 8) = o;
    }
}

// Flash attention: 8 waves x 32 q-rows, KVBLK=128, 16 iters, bias in LDS,
// fixed-shift softmax (no max tracking), row-sum via ones-MFMA.
__global__ __launch_bounds__(512) void attn_kernel(
    const bf16* __restrict__ qkv, const bf16* __restrict__ vT,
    const float* __restrict__ bias, const int* __restrict__ mask,
    bf16* __restrict__ concat)
{
    const int w = blockIdx.x;                 // 0..511
    const int nw = (w & 7) * 64 + (w >> 3);
    const int qt = nw & 7, bh = nw >> 3;
    const int b = bh >> 4, h = bh & 15;
    const int tid = threadIdx.x;
    const int lane = tid & 63, wv = tid >> 6;
    const int lq = lane & 31, hi = lane >> 5;

    __shared__ bf16 Ks[2][128 * 64];
    __shared__ bf16 Vs[2][64 * 128];
    __shared__ float Bl[2048 + 16];

    const size_t tok0 = (size_t)b * SS;
    const int qrow0 = qt * 256 + wv * 32;

    const int qpad = mask[tok0 + qrow0 + lq];
    bf16x8 qf[4];
    {
        const bf16* qp = qkv + (tok0 + qrow0 + lq) * QKVLD + h * 64 + hi * 8;
#pragma unroll
        for (int ks = 0; ks < 4; ++ks) {
            bf16x8 v = *reinterpret_cast<const bf16x8*>(qp + ks * 16);
#pragma unroll
            for (int j = 0; j < 8; ++j)
                v[j] = qpad ? (bf16)0.f : (bf16)((float)v[j] * LOG2E_DIV8);
            qf[ks] = v;
        }
    }
    bf16x8 ones;
#pragma unroll
    for (int j = 0; j < 8; ++j) ones[j] = (bf16)1.0f;

    f32x16 oA, oB, lacc;
#pragma unroll
    for (int e = 0; e < 16; ++e) { oA[e] = 0.f; oB[e] = 0.f; lacc[e] = 0.f; }

    const int c0 = tid, c1 = tid + 512;
    const int kr0 = c0 >> 3, kc0 = c0 & 7, kr1 = c1 >> 3, kc1 = c1 & 7;
    const int vr0 = c0 >> 4, vc0 = c0 & 15, vr1 = c1 >> 4, vc1 = c1 & 15;
    const char* kSrc = (const char*)(qkv + 1024 + h * 64);
    const char* vSrc = (const char*)(vT + (size_t)bh * 64 * SS);
    const size_t kOff0 = (tok0 + kr0) * (QKVLD * 2) + ((kc0 * 16) ^ ((kr0 & 7) << 4));
    const size_t kOff1 = (tok0 + kr1) * (QKVLD * 2) + ((kc1 * 16) ^ ((kr1 & 7) << 4));
    const size_t vOff0 = (size_t)vr0 * (SS * 2) + ((vc0 * 16) ^ ((vr0 & 15) << 4));
    const size_t vOff1 = (size_t)vr1 * (SS * 2) + ((vc1 * 16) ^ ((vr1 & 15) << 4));

    const int kxor = (hi * 16) ^ ((lq & 7) << 4);
    const int vxor = (hi * 16) ^ ((lq & 15) << 4);
    const int bmask = qpad ? 0 : -1;
    const char* bbase = (const char*)Bl + (qpad ? 8192 : hi * 64);

    gload_lds16(kSrc + kOff0, (char*)Ks[0] + c0 * 16);
    gload_lds16(kSrc + kOff1, (char*)Ks[0] + c1 * 16);
    gload_lds16(vSrc + vOff0, (char*)Vs[0] + c0 * 16);
    gload_lds16(vSrc + vOff1, (char*)Vs[0] + c1 * 16);
    gload_lds16((const char*)(bias + (size_t)b * 2048) + tid * 16, (char*)Bl + tid * 16);
    if (tid < 4) {
        f32x4 z = {-CSHIFT, -CSHIFT, -CSHIFT, -CSHIFT};
        *reinterpret_cast<f32x4*>((char*)Bl + 8192 + tid * 16) = z;
    }
    __syncthreads();

    for (int kt = 0; kt < 16; ++kt) {
        const int cur = kt & 1;

        if (kt < 15) {
            const size_t kAdv = (size_t)(kt + 1) * 128 * (QKVLD * 2);
            const size_t vAdv = (size_t)(kt + 1) * 256;
            gload_lds16(kSrc + kOff0 + kAdv, (char*)Ks[cur ^ 1] + c0 * 16);
            gload_lds16(kSrc + kOff1 + kAdv, (char*)Ks[cur ^ 1] + c1 * 16);
            gload_lds16(vSrc + vOff0 + vAdv, (char*)Vs[cur ^ 1] + c0 * 16);
            gload_lds16(vSrc + vOff1 + vAdv, (char*)Vs[cur ^ 1] + c1 * 16);
        }

        const char* kB = (const char*)Ks[cur];
        const char* vB = (const char*)Vs[cur];
        const int bo = (kt * 512) & bmask;

        f32x16 s[4];
#pragma unroll
        for (int kg = 0; kg < 4; ++kg)
            s[kg] = *reinterpret_cast<const f32x16*>(bbase + bo + ((kg * 128) & bmask));
        __builtin_amdgcn_s_setprio(1);
#pragma unroll
        for (int kg = 0; kg < 4; ++kg) {
            const char* kR = kB + (kg * 32 + lq) * 128;
#pragma unroll
            for (int ks = 0; ks < 4; ++ks) {
                bf16x8 kf = *reinterpret_cast<const bf16x8*>(kR + (kxor ^ (ks * 32)));
                s[kg] = __builtin_amdgcn_mfma_f32_32x32x16_bf16(kf, qf[ks], s[kg], 0, 0, 0);
            }
        }
        __builtin_amdgcn_s_setprio(0);

#pragma unroll
        for (int kg = 0; kg < 4; ++kg)
#pragma unroll
            for (int e = 0; e < 16; ++e)
                s[kg][e] = fexp2(s[kg][e]);

        __builtin_amdgcn_s_setprio(1);
#pragma unroll
        for (int kk = 0; kk < 8; ++kk) {
            const float* pp = (const float*)&s[kk >> 1];
            const int ks2 = kk & 1;
            uint32_t c0p = cvtpk(pp[8 * ks2 + 0], pp[8 * ks2 + 1]);
            uint32_t c1p = cvtpk(pp[8 * ks2 + 2], pp[8 * ks2 + 3]);
            uint32_t c2p = cvtpk(pp[8 * ks2 + 4], pp[8 * ks2 + 5]);
            uint32_t c3p = cvtpk(pp[8 * ks2 + 6], pp[8 * ks2 + 7]);
            asm("v_permlane32_swap_b32 %0, %1" : "+v"(c0p), "+v"(c2p));
            asm("v_permlane32_swap_b32 %0, %1" : "+v"(c1p), "+v"(c3p));
            union { uint32_t u[4]; bf16x8 v; } pu;
            pu.u[0] = c0p; pu.u[1] = c1p; pu.u[2] = c2p; pu.u[3] = c3p;
            bf16x8 vf0 = *reinterpret_cast<const bf16x8*>(
                vB + (lq)*256 + (vxor ^ (kk * 32)));
            bf16x8 vf1 = *reinterpret_cast<const bf16x8*>(
                vB + (32 + lq) * 256 + (vxor ^ (kk * 32)));
            oA = __builtin_amdgcn_mfma_f32_32x32x16_bf16(vf0, pu.v, oA, 0, 0, 0);
            oB = __builtin_amdgcn_mfma_f32_32x32x16_bf16(vf1, pu.v, oB, 0, 0, 0);
            lacc = __builtin_amdgcn_mfma_f32_32x32x16_bf16(ones, pu.v, lacc, 0, 0, 0);
        }
        __builtin_amdgcn_s_setprio(0);

        if (kt < 15) __syncthreads();
    }

    float inv = 1.0f / lacc[0];
#pragma unroll
    for (int g = 0; g < 4; ++g) {
        bf16x4 w0, w1;
#pragma unroll
        for (int r = 0; r < 4; ++r) {
            w0[r] = (bf16)(oA[g * 4 + r] * inv);
            w1[r] = (bf16)(oB[g * 4 + r] * inv);
        }
        int d0 = 4 * hi + 8 * g;
        bf16* cp = concat + (tok0 + qrow0 + lq) * QKVLD + h * 64 + d0;
        *reinterpret_cast<bf16x4*>(cp) = w0;
        *reinterpret_cast<bf16x4*>(cp + 32) = w1;
    }
}

extern "C" void kernel_launch(void* const* d_in, const int* in_sizes, int n_in,
                              void* d_out, int out_size, void* d_ws, size_t ws_size,
                              hipStream_t stream)
{
    const float* x  = (const float*)d_in[0];
    const int* mask = (const int*)d_in[1];
    const float* Wq = (const float*)d_in[2];
    const float* Wk = (const float*)d_in[3];
    const float* Wv = (const float*)d_in[4];
    const float* Wo = (const float*)d_in[5];
    float* out = (float*)d_out;

    // workspace (72 MiB):
    //  [0,16)  xb -> vT (xb dead after QKV gemm)
    //  [16,22) wqkv -> bias (dead after QKV gemm)   [22,24) wob
    //  [24,72) qkv [8192][3072]; v-cols (2048..3071) become concat after vtrans
    char* ws = (char*)d_ws;
    bf16* xb    = (bf16*)(ws);
    bf16* wqkv  = (bf16*)(ws + (16ull << 20));
    bf16* wob   = (bf16*)(ws + (22ull << 20));
    bf16* qkv   = (bf16*)(ws + (24ull << 20));
    bf16* vT    = xb;
    float* bias = (float*)wqkv;
    bf16* concat = qkv + 2048;   // strided [8192][.] within qkv, stride 3072

    cvt_kernel<<<dim3((NTOK * DM / 8) / 256), 256, 0, stream>>>(x, xb, NTOK * DM / 8);
    wcvt_kernel<<<dim3(2048), 256, 0, stream>>>(Wq, Wk, Wv, Wo, wqkv, wob);

    // fused QKV projection: 256^2 counted-vmcnt structure, grid (12, 32) = 384
    gemm_bt256<<<dim3(QKVLD / 256, NTOK / 256), 512, 0, stream>>>(
        xb, DM, wqkv, qkv, NTOK, QKVLD, DM);

    vtrans_kernel<<<dim3(SS / 64, BB * NH), 256, 0, stream>>>(qkv + 2048, QKVLD, vT);
    biasprep_kernel<<<dim3(32), 256, 0, stream>>>(mask, bias);

    attn_kernel<<<dim3((SS / 256) * (BB * NH)), 512, 0, stream>>>(
        qkv, vT, bias, mask, concat);

    // output projection: out = concat(lda=3072) @ wob^T
    gemm_bt<float><<<dim3(DM / 128, NTOK / 128), 256, 0, stream>>>(
        concat, QKVLD, wob, out, NTOK, DM, DM);
}

// Round 10
// 194.605 us; speedup vs baseline: 1.0772x; 1.0772x over previous
//
#include <hip/hip_runtime.h>
#include <stdint.h>

// MultiHeadAttention: B=4, S=2048, D_MODEL=1024, H=16, d_k=d_v=64
// Round 10: revert QKV to proven 128^2 gemm (256^2 coarse structure regressed:
// tail quantization at 384 blocks/CU + no fine interleave). Attn: remove the
// lacc ones-MFMA (20% of matrix work) — psum via VALU adds in the exp loop.

typedef __bf16 bf16;
typedef __bf16 bf16x8 __attribute__((ext_vector_type(8)));
typedef __bf16 bf16x4 __attribute__((ext_vector_type(4)));
typedef float f32x4 __attribute__((ext_vector_type(4)));
typedef float f32x16 __attribute__((ext_vector_type(16)));

#define DM    1024
#define NH    16
#define SS    2048
#define BB    4
#define NTOK  8192
#define QKVLD 3072
#define LOG2E_DIV8 0.18033688011112042f   // log2(e)/8: scale folded into Q, exp2 domain
#define CSHIFT 12.0f                      // fixed softmax shift (folded into bias)

__device__ __forceinline__ int swz(int row, int byteoff) {
    return byteoff ^ ((row & 7) << 4);
}
__device__ __forceinline__ float fexp2(float x) {
    float r; asm("v_exp_f32 %0, %1" : "=v"(r) : "v"(x)); return r;
}
__device__ __forceinline__ uint32_t cvtpk(float lo, float hi_) {
    uint32_t r; asm("v_cvt_pk_bf16_f32 %0, %1, %2" : "=v"(r) : "v"(lo), "v"(hi_)); return r;
}
__device__ __forceinline__ void gload_lds16(const void* g, void* l) {
    __builtin_amdgcn_global_load_lds(
        (const __attribute__((address_space(1))) uint32_t*)g,
        (__attribute__((address_space(3))) uint32_t*)l, 16, 0, 0);
}

__global__ void cvt_kernel(const float* __restrict__ in, bf16* __restrict__ out, int n8) {
    int i = blockIdx.x * blockDim.x + threadIdx.x;
    if (i >= n8) return;
    const float4* p = reinterpret_cast<const float4*>(in) + (size_t)i * 2;
    float4 a = p[0], b = p[1];
    bf16x8 o;
    o[0] = (bf16)a.x; o[1] = (bf16)a.y; o[2] = (bf16)a.z; o[3] = (bf16)a.w;
    o[4] = (bf16)b.x; o[5] = (bf16)b.y; o[6] = (bf16)b.z; o[7] = (bf16)b.w;
    reinterpret_cast<bf16x8*>(out)[i] = o;
}

// all 4 weight matrices (1M fp32 each) in one launch
__global__ void wcvt_kernel(const float* __restrict__ wq, const float* __restrict__ wk,
                            const float* __restrict__ wv, const float* __restrict__ wo,
                            bf16* __restrict__ wqkv, bf16* __restrict__ wob) {
    int i = blockIdx.x * blockDim.x + threadIdx.x;   // 8-elem group id, 4*131072 total
    int seg = i >> 17, off = i & 131071;
    const float* src = (seg == 0) ? wq : (seg == 1) ? wk : (seg == 2) ? wv : wo;
    bf16* dst = (seg < 3) ? (wqkv + (size_t)seg * DM * DM) : wob;
    const float4* p = reinterpret_cast<const float4*>(src) + (size_t)off * 2;
    float4 a = p[0], b = p[1];
    bf16x8 o;
    o[0] = (bf16)a.x; o[1] = (bf16)a.y; o[2] = (bf16)a.z; o[3] = (bf16)a.w;
    o[4] = (bf16)b.x; o[5] = (bf16)b.y; o[6] = (bf16)b.z; o[7] = (bf16)b.w;
    reinterpret_cast<bf16x8*>(dst)[off] = o;
}

// bias[b4][kt16][kg4][hi2][e16]: -inf where key padded, else -CSHIFT.
__global__ void biasprep_kernel(const int* __restrict__ mask, float* __restrict__ bias) {
    int idx = blockIdx.x * blockDim.x + threadIdx.x;
    if (idx >= 4 * 2048) return;
    int e = idx & 15, hi = (idx >> 4) & 1, kg = (idx >> 5) & 3;
    int kt = (idx >> 7) & 15, b = idx >> 11;
    int key = kt * 128 + kg * 32 + 4 * hi + 8 * (e >> 2) + (e & 3);
    bias[idx] = mask[b * SS + key] ? -__builtin_inff() : -CSHIFT;
}

// C[M,N] = A[M,K](lda) * Bm[N,K]^T. 128x128 tile, BK=64, 4 waves, 16x16x32 MFMA.
template <typename OT>
__global__ __launch_bounds__(256) void gemm_bt(
    const bf16* __restrict__ A, int lda, const bf16* __restrict__ Bm, OT* __restrict__ C,
    int M, int N, int K)
{
    __shared__ bf16 As[128 * 64];
    __shared__ bf16 Bs[128 * 64];

    const int nwg = gridDim.x * gridDim.y;
    const int wg = blockIdx.y * gridDim.x + blockIdx.x;
    const int nsw = (wg & 7) * (nwg >> 3) + (wg >> 3);
    const int tn = nsw % gridDim.x, tm = nsw / gridDim.x;

    const int tid = threadIdx.x;
    const int lane = tid & 63, wv = tid >> 6;
    const int wr = wv >> 1, wc = wv & 1;
    const int lr = lane & 15, lg = lane >> 4;

    const f32x4 zero = {0.f, 0.f, 0.f, 0.f};
    f32x4 acc[4][4];
#pragma unroll
    for (int mi = 0; mi < 4; ++mi)
#pragma unroll
        for (int ni = 0; ni < 4; ++ni) acc[mi][ni] = zero;

    const char* Abase = (const char*)(A + (size_t)(tm * 128) * lda);
    const char* Bbase = (const char*)(Bm + (size_t)(tn * 128) * K);

    for (int k0 = 0; k0 < K; k0 += 64) {
#pragma unroll
        for (int i = 0; i < 4; ++i) {
            int idx = tid + 256 * i;
            int row = idx >> 3, ch = idx & 7;
            int gcol = (ch * 16) ^ ((row & 7) << 4);
            gload_lds16(Abase + (size_t)row * (lda * 2) + k0 * 2 + gcol, (char*)As + idx * 16);
            gload_lds16(Bbase + (size_t)row * (K * 2) + k0 * 2 + gcol, (char*)Bs + idx * 16);
        }
        __syncthreads();

#pragma unroll
        for (int ks = 0; ks < 2; ++ks) {
            bf16x8 af[4], bfr[4];
#pragma unroll
            for (int mi = 0; mi < 4; ++mi) {
                int row = wr * 64 + mi * 16 + lr;
                af[mi] = *reinterpret_cast<const bf16x8*>(
                    (char*)As + swz(row, row * 128 + ks * 64 + lg * 16));
            }
#pragma unroll
            for (int ni = 0; ni < 4; ++ni) {
                int row = wc * 64 + ni * 16 + lr;
                bfr[ni] = *reinterpret_cast<const bf16x8*>(
                    (char*)Bs + swz(row, row * 128 + ks * 64 + lg * 16));
            }
#pragma unroll
            for (int mi = 0; mi < 4; ++mi)
#pragma unroll
                for (int ni = 0; ni < 4; ++ni)
                    acc[mi][ni] = __builtin_amdgcn_mfma_f32_16x16x32_bf16(
                        af[mi], bfr[ni], acc[mi][ni], 0, 0, 0);
        }
        __syncthreads();
    }

#pragma unroll
    for (int mi = 0; mi < 4; ++mi)
#pragma unroll
        for (int ni = 0; ni < 4; ++ni)
#pragma unroll
            for (int r = 0; r < 4; ++r) {
                int row = tm * 128 + wr * 64 + mi * 16 + lg * 4 + r;
                int col = tn * 128 + wc * 64 + ni * 16 + lr;
                C[(size_t)row * N + col] = (OT)acc[mi][ni][r];
            }
}

// Transpose V: vb[token][ldv] head-cols -> vT[(bh*64+d)][s]
__global__ __launch_bounds__(256) void vtrans_kernel(
    const bf16* __restrict__ vb, int ldv, bf16* __restrict__ vT)
{
    const int st = blockIdx.x, bh = blockIdx.y;
    const int b = bh >> 4, h = bh & 15;
    const int tid = threadIdx.x;
    __shared__ bf16 T[64 * 64];
#pragma unroll
    for (int i = 0; i < 2; ++i) {
        int idx = tid + 256 * i;
        int s = idx >> 3, ch = idx & 7;
        bf16x8 v = *reinterpret_cast<const bf16x8*>(
            vb + (size_t)(b * SS + st * 64 + s) * ldv + h * 64 + ch * 8);
        *reinterpret_cast<bf16x8*>((char*)T + swz(s, s * 128 + ch * 16)) = v;
    }
    __syncthreads();
#pragma unroll
    for (int i = 0; i < 2; ++i) {
        int idx = tid + 256 * i;
        int d = idx >> 3, ch = idx & 7;
        bf16x8 o;
#pragma unroll
        for (int j = 0; j < 8; ++j) {
            int s = ch * 8 + j;
            o[j] = *reinterpret_cast<const bf16*>((char*)T + swz(s, s * 128 + d * 2));
        }
        *reinterpret_cast<bf16x8*>(vT + ((size_t)bh * 64 + d) * SS + st * 64 + ch * 8) = o;
    }
}

// Flash attention: 8 waves x 32 q-rows, KVBLK=128, 16 iters, bias in LDS,
// fixed-shift softmax; psum on VALU (fused into exp loop), no lacc MFMA.
__global__ __launch_bounds__(512) void attn_kernel(
    const bf16* __restrict__ qkv, const bf16* __restrict__ vT,
    const float* __restrict__ bias, const int* __restrict__ mask,
    bf16* __restrict__ concat)
{
    const int w = blockIdx.x;                 // 0..511
    const int nw = (w & 7) * 64 + (w >> 3);
    const int qt = nw & 7, bh = nw >> 3;
    const int b = bh >> 4, h = bh & 15;
    const int tid = threadIdx.x;
    const int lane = tid & 63, wv = tid >> 6;
    const int lq = lane & 31, hi = lane >> 5;

    __shared__ bf16 Ks[2][128 * 64];
    __shared__ bf16 Vs[2][64 * 128];
    __shared__ float Bl[2048 + 16];

    const size_t tok0 = (size_t)b * SS;
    const int qrow0 = qt * 256 + wv * 32;

    const int qpad = mask[tok0 + qrow0 + lq];
    bf16x8 qf[4];
    {
        const bf16* qp = qkv + (tok0 + qrow0 + lq) * QKVLD + h * 64 + hi * 8;
#pragma unroll
        for (int ks = 0; ks < 4; ++ks) {
            bf16x8 v = *reinterpret_cast<const bf16x8*>(qp + ks * 16);
#pragma unroll
            for (int j = 0; j < 8; ++j)
                v[j] = qpad ? (bf16)0.f : (bf16)((float)v[j] * LOG2E_DIV8);
            qf[ks] = v;
        }
    }

    f32x16 oA, oB;
#pragma unroll
    for (int e = 0; e < 16; ++e) { oA[e] = 0.f; oB[e] = 0.f; }
    float lrow = 0.f;

    const int c0 = tid, c1 = tid + 512;
    const int kr0 = c0 >> 3, kc0 = c0 & 7, kr1 = c1 >> 3, kc1 = c1 & 7;
    const int vr0 = c0 >> 4, vc0 = c0 & 15, vr1 = c1 >> 4, vc1 = c1 & 15;
    const char* kSrc = (const char*)(qkv + 1024 + h * 64);
    const char* vSrc = (const char*)(vT + (size_t)bh * 64 * SS);
    const size_t kOff0 = (tok0 + kr0) * (QKVLD * 2) + ((kc0 * 16) ^ ((kr0 & 7) << 4));
    const size_t kOff1 = (tok0 + kr1) * (QKVLD * 2) + ((kc1 * 16) ^ ((kr1 & 7) << 4));
    const size_t vOff0 = (size_t)vr0 * (SS * 2) + ((vc0 * 16) ^ ((vr0 & 15) << 4));
    const size_t vOff1 = (size_t)vr1 * (SS * 2) + ((vc1 * 16) ^ ((vr1 & 15) << 4));

    const int kxor = (hi * 16) ^ ((lq & 7) << 4);
    const int vxor = (hi * 16) ^ ((lq & 15) << 4);
    const int bmask = qpad ? 0 : -1;
    const char* bbase = (const char*)Bl + (qpad ? 8192 : hi * 64);

    gload_lds16(kSrc + kOff0, (char*)Ks[0] + c0 * 16);
    gload_lds16(kSrc + kOff1, (char*)Ks[0] + c1 * 16);
    gload_lds16(vSrc + vOff0, (char*)Vs[0] + c0 * 16);
    gload_lds16(vSrc + vOff1, (char*)Vs[0] + c1 * 16);
    gload_lds16((const char*)(bias + (size_t)b * 2048) + tid * 16, (char*)Bl + tid * 16);
    if (tid < 4) {
        f32x4 z = {-CSHIFT, -CSHIFT, -CSHIFT, -CSHIFT};
        *reinterpret_cast<f32x4*>((char*)Bl + 8192 + tid * 16) = z;
    }
    __syncthreads();

    for (int kt = 0; kt < 16; ++kt) {
        const int cur = kt & 1;

        if (kt < 15) {
            const size_t kAdv = (size_t)(kt + 1) * 128 * (QKVLD * 2);
            const size_t vAdv = (size_t)(kt + 1) * 256;
            gload_lds16(kSrc + kOff0 + kAdv, (char*)Ks[cur ^ 1] + c0 * 16);
            gload_lds16(kSrc + kOff1 + kAdv, (char*)Ks[cur ^ 1] + c1 * 16);
            gload_lds16(vSrc + vOff0 + vAdv, (char*)Vs[cur ^ 1] + c0 * 16);
            gload_lds16(vSrc + vOff1 + vAdv, (char*)Vs[cur ^ 1] + c1 * 16);
        }

        const char* kB = (const char*)Ks[cur];
        const char* vB = (const char*)Vs[cur];
        const int bo = (kt * 512) & bmask;

        // QK^T: S^T[128 key][32 q], C-init = bias-with-shift from LDS
        f32x16 s[4];
#pragma unroll
        for (int kg = 0; kg < 4; ++kg)
            s[kg] = *reinterpret_cast<const f32x16*>(bbase + bo + ((kg * 128) & bmask));
        __builtin_amdgcn_s_setprio(1);
#pragma unroll
        for (int kg = 0; kg < 4; ++kg) {
            const char* kR = kB + (kg * 32 + lq) * 128;
#pragma unroll
            for (int ks = 0; ks < 4; ++ks) {
                bf16x8 kf = *reinterpret_cast<const bf16x8*>(kR + (kxor ^ (ks * 32)));
                s[kg] = __builtin_amdgcn_mfma_f32_32x32x16_bf16(kf, qf[ks], s[kg], 0, 0, 0);
            }
        }
        __builtin_amdgcn_s_setprio(0);

        // p = exp2(s) in place; psum accumulated on VALU (4-way partials)
        float ps[4] = {0.f, 0.f, 0.f, 0.f};
#pragma unroll
        for (int kg = 0; kg < 4; ++kg)
#pragma unroll
            for (int e = 0; e < 16; ++e) {
                float t = fexp2(s[kg][e]);
                s[kg][e] = t;
                ps[e & 3] += t;
            }
        float psum = (ps[0] + ps[1]) + (ps[2] + ps[3]);
        psum += __shfl_xor(psum, 32);
        lrow += psum;

        // pack P -> bf16 B-fragments; PV MFMA
        __builtin_amdgcn_s_setprio(1);
#pragma unroll
        for (int kk = 0; kk < 8; ++kk) {
            const float* pp = (const float*)&s[kk >> 1];
            const int ks2 = kk & 1;
            uint32_t c0p = cvtpk(pp[8 * ks2 + 0], pp[8 * ks2 + 1]);
            uint32_t c1p = cvtpk(pp[8 * ks2 + 2], pp[8 * ks2 + 3]);
            uint32_t c2p = cvtpk(pp[8 * ks2 + 4], pp[8 * ks2 + 5]);
            uint32_t c3p = cvtpk(pp[8 * ks2 + 6], pp[8 * ks2 + 7]);
            asm("v_permlane32_swap_b32 %0, %1" : "+v"(c0p), "+v"(c2p));
            asm("v_permlane32_swap_b32 %0, %1" : "+v"(c1p), "+v"(c3p));
            union { uint32_t u[4]; bf16x8 v; } pu;
            pu.u[0] = c0p; pu.u[1] = c1p; pu.u[2] = c2p; pu.u[3] = c3p;
            bf16x8 vf0 = *reinterpret_cast<const bf16x8*>(
                vB + (lq)*256 + (vxor ^ (kk * 32)));
            bf16x8 vf1 = *reinterpret_cast<const bf16x8*>(
                vB + (32 + lq) * 256 + (vxor ^ (kk * 32)));
            oA = __builtin_amdgcn_mfma_f32_32x32x16_bf16(vf0, pu.v, oA, 0, 0, 0);
            oB = __builtin_amdgcn_mfma_f32_32x32x16_bf16(vf1, pu.v, oB, 0, 0, 0);
        }
        __builtin_amdgcn_s_setprio(0);

        if (kt < 15) __syncthreads();
    }

    float inv = 1.0f / lrow;
#pragma unroll
    for (int g = 0; g < 4; ++g) {
        bf16x4 w0, w1;
#pragma unroll
        for (int r = 0; r < 4; ++r) {
            w0[r] = (bf16)(oA[g * 4 + r] * inv);
            w1[r] = (bf16)(oB[g * 4 + r] * inv);
        }
        int d0 = 4 * hi + 8 * g;
        bf16* cp = concat + (tok0 + qrow0 + lq) * QKVLD + h * 64 + d0;
        *reinterpret_cast<bf16x4*>(cp) = w0;
        *reinterpret_cast<bf16x4*>(cp + 32) = w1;
    }
}

extern "C" void kernel_launch(void* const* d_in, const int* in_sizes, int n_in,
                              void* d_out, int out_size, void* d_ws, size_t ws_size,
                              hipStream_t stream)
{
    const float* x  = (const float*)d_in[0];
    const int* mask = (const int*)d_in[1];
    const float* Wq = (const float*)d_in[2];
    const float* Wk = (const float*)d_in[3];
    const float* Wv = (const float*)d_in[4];
    const float* Wo = (const float*)d_in[5];
    float* out = (float*)d_out;

    // workspace (72 MiB):
    //  [0,16)  xb -> vT (xb dead after QKV gemm)
    //  [16,22) wqkv -> bias (dead after QKV gemm)   [22,24) wob
    //  [24,72) qkv [8192][3072]; v-cols (2048..3071) become concat after vtrans
    char* ws = (char*)d_ws;
    bf16* xb    = (bf16*)(ws);
    bf16* wqkv  = (bf16*)(ws + (16ull << 20));
    bf16* wob   = (bf16*)(ws + (22ull << 20));
    bf16* qkv   = (bf16*)(ws + (24ull << 20));
    bf16* vT    = xb;
    float* bias = (float*)wqkv;
    bf16* concat = qkv + 2048;   // strided [8192][.] within qkv, stride 3072

    cvt_kernel<<<dim3((NTOK * DM / 8) / 256), 256, 0, stream>>>(x, xb, NTOK * DM / 8);
    wcvt_kernel<<<dim3(2048), 256, 0, stream>>>(Wq, Wk, Wv, Wo, wqkv, wob);

    // fused QKV projection: 128^2 tiles (reverted from 256^2 — round-9 regression)
    gemm_bt<bf16><<<dim3(QKVLD / 128, NTOK / 128), 256, 0, stream>>>(
        xb, DM, wqkv, qkv, NTOK, QKVLD, DM);

    vtrans_kernel<<<dim3(SS / 64, BB * NH), 256, 0, stream>>>(qkv + 2048, QKVLD, vT);
    biasprep_kernel<<<dim3(32), 256, 0, stream>>>(mask, bias);

    attn_kernel<<<dim3((SS / 256) * (BB * NH)), 512, 0, stream>>>(
        qkv, vT, bias, mask, concat);

    // output projection: out = concat(lda=3072) @ wob^T
    gemm_bt<float><<<dim3(DM / 128, NTOK / 128), 256, 0, stream>>>(
        concat, QKVLD, wob, out, NTOK, DM, DM);
}

// Round 13
// 189.430 us; speedup vs baseline: 1.1066x; 1.0273x over previous
//
#include <hip/hip_runtime.h>
#include <stdint.h>

// MultiHeadAttention: B=4, S=2048, D_MODEL=1024, H=16, d_k=d_v=64
// Round 13: revert to round-10 green structure (two-tile pipeline had a
// deterministic bug — identical absmax across barrier variants — abandoned).
// Attn deltas vs round 10, both math-preserving: (a) kg-fused exp/pack/PV so
// exp(kg+1) can overlap PV(kg) in the scheduler; (b) l-reduction deferred to
// a single end-of-kernel shfl (linearity of shfl_xor over sums).

typedef __bf16 bf16;
typedef __bf16 bf16x8 __attribute__((ext_vector_type(8)));
typedef __bf16 bf16x4 __attribute__((ext_vector_type(4)));
typedef float f32x4 __attribute__((ext_vector_type(4)));
typedef float f32x16 __attribute__((ext_vector_type(16)));

#define DM    1024
#define NH    16
#define SS    2048
#define BB    4
#define NTOK  8192
#define QKVLD 3072
#define LOG2E_DIV8 0.18033688011112042f   // log2(e)/8: scale folded into Q, exp2 domain
#define CSHIFT 12.0f                      // fixed softmax shift (folded into bias)

__device__ __forceinline__ int swz(int row, int byteoff) {
    return byteoff ^ ((row & 7) << 4);
}
__device__ __forceinline__ float fexp2(float x) {
    float r; asm("v_exp_f32 %0, %1" : "=v"(r) : "v"(x)); return r;
}
__device__ __forceinline__ uint32_t cvtpk(float lo, float hi_) {
    uint32_t r; asm("v_cvt_pk_bf16_f32 %0, %1, %2" : "=v"(r) : "v"(lo), "v"(hi_)); return r;
}
__device__ __forceinline__ void gload_lds16(const void* g, void* l) {
    __builtin_amdgcn_global_load_lds(
        (const __attribute__((address_space(1))) uint32_t*)g,
        (__attribute__((address_space(3))) uint32_t*)l, 16, 0, 0);
}

__global__ void cvt_kernel(const float* __restrict__ in, bf16* __restrict__ out, int n8) {
    int i = blockIdx.x * blockDim.x + threadIdx.x;
    if (i >= n8) return;
    const float4* p = reinterpret_cast<const float4*>(in) + (size_t)i * 2;
    float4 a = p[0], b = p[1];
    bf16x8 o;
    o[0] = (bf16)a.x; o[1] = (bf16)a.y; o[2] = (bf16)a.z; o[3] = (bf16)a.w;
    o[4] = (bf16)b.x; o[5] = (bf16)b.y; o[6] = (bf16)b.z; o[7] = (bf16)b.w;
    reinterpret_cast<bf16x8*>(out)[i] = o;
}

// all 4 weight matrices (1M fp32 each) in one launch
__global__ void wcvt_kernel(const float* __restrict__ wq, const float* __restrict__ wk,
                            const float* __restrict__ wv, const float* __restrict__ wo,
                            bf16* __restrict__ wqkv, bf16* __restrict__ wob) {
    int i = blockIdx.x * blockDim.x + threadIdx.x;   // 8-elem group id, 4*131072 total
    int seg = i >> 17, off = i & 131071;
    const float* src = (seg == 0) ? wq : (seg == 1) ? wk : (seg == 2) ? wv : wo;
    bf16* dst = (seg < 3) ? (wqkv + (size_t)seg * DM * DM) : wob;
    const float4* p = reinterpret_cast<const float4*>(src) + (size_t)off * 2;
    float4 a = p[0], b = p[1];
    bf16x8 o;
    o[0] = (bf16)a.x; o[1] = (bf16)a.y; o[2] = (bf16)a.z; o[3] = (bf16)a.w;
    o[4] = (bf16)b.x; o[5] = (bf16)b.y; o[6] = (bf16)b.z; o[7] = (bf16)b.w;
    reinterpret_cast<bf16x8*>(dst)[off] = o;
}

// bias[b4][kt16][kg4][hi2][e16]: -inf where key padded, else -CSHIFT.
__global__ void biasprep_kernel(const int* __restrict__ mask, float* __restrict__ bias) {
    int idx = blockIdx.x * blockDim.x + threadIdx.x;
    if (idx >= 4 * 2048) return;
    int e = idx & 15, hi = (idx >> 4) & 1, kg = (idx >> 5) & 3;
    int kt = (idx >> 7) & 15, b = idx >> 11;
    int key = kt * 128 + kg * 32 + 4 * hi + 8 * (e >> 2) + (e & 3);
    bias[idx] = mask[b * SS + key] ? -__builtin_inff() : -CSHIFT;
}

// C[M,N] = A[M,K](lda) * Bm[N,K]^T. 128x128 tile, BK=64, 4 waves, 16x16x32 MFMA.
template <typename OT>
__global__ __launch_bounds__(256) void gemm_bt(
    const bf16* __restrict__ A, int lda, const bf16* __restrict__ Bm, OT* __restrict__ C,
    int M, int N, int K)
{
    __shared__ bf16 As[128 * 64];
    __shared__ bf16 Bs[128 * 64];

    const int nwg = gridDim.x * gridDim.y;
    const int wg = blockIdx.y * gridDim.x + blockIdx.x;
    const int nsw = (wg & 7) * (nwg >> 3) + (wg >> 3);
    const int tn = nsw % gridDim.x, tm = nsw / gridDim.x;

    const int tid = threadIdx.x;
    const int lane = tid & 63, wv = tid >> 6;
    const int wr = wv >> 1, wc = wv & 1;
    const int lr = lane & 15, lg = lane >> 4;

    const f32x4 zero = {0.f, 0.f, 0.f, 0.f};
    f32x4 acc[4][4];
#pragma unroll
    for (int mi = 0; mi < 4; ++mi)
#pragma unroll
        for (int ni = 0; ni < 4; ++ni) acc[mi][ni] = zero;

    const char* Abase = (const char*)(A + (size_t)(tm * 128) * lda);
    const char* Bbase = (const char*)(Bm + (size_t)(tn * 128) * K);

    for (int k0 = 0; k0 < K; k0 += 64) {
#pragma unroll
        for (int i = 0; i < 4; ++i) {
            int idx = tid + 256 * i;
            int row = idx >> 3, ch = idx & 7;
            int gcol = (ch * 16) ^ ((row & 7) << 4);
            gload_lds16(Abase + (size_t)row * (lda * 2) + k0 * 2 + gcol, (char*)As + idx * 16);
            gload_lds16(Bbase + (size_t)row * (K * 2) + k0 * 2 + gcol, (char*)Bs + idx * 16);
        }
        __syncthreads();

#pragma unroll
        for (int ks = 0; ks < 2; ++ks) {
            bf16x8 af[4], bfr[4];
#pragma unroll
            for (int mi = 0; mi < 4; ++mi) {
                int row = wr * 64 + mi * 16 + lr;
                af[mi] = *reinterpret_cast<const bf16x8*>(
                    (char*)As + swz(row, row * 128 + ks * 64 + lg * 16));
            }
#pragma unroll
            for (int ni = 0; ni < 4; ++ni) {
                int row = wc * 64 + ni * 16 + lr;
                bfr[ni] = *reinterpret_cast<const bf16x8*>(
                    (char*)Bs + swz(row, row * 128 + ks * 64 + lg * 16));
            }
#pragma unroll
            for (int mi = 0; mi < 4; ++mi)
#pragma unroll
                for (int ni = 0; ni < 4; ++ni)
                    acc[mi][ni] = __builtin_amdgcn_mfma_f32_16x16x32_bf16(
                        af[mi], bfr[ni], acc[mi][ni], 0, 0, 0);
        }
        __syncthreads();
    }

#pragma unroll
    for (int mi = 0; mi < 4; ++mi)
#pragma unroll
        for (int ni = 0; ni < 4; ++ni)
#pragma unroll
            for (int r = 0; r < 4; ++r) {
                int row = tm * 128 + wr * 64 + mi * 16 + lg * 4 + r;
                int col = tn * 128 + wc * 64 + ni * 16 + lr;
                C[(size_t)row * N + col] = (OT)acc[mi][ni][r];
            }
}

// Transpose V: vb[token][ldv] head-cols -> vT[(bh*64+d)][s]
__global__ __launch_bounds__(256) void vtrans_kernel(
    const bf16* __restrict__ vb, int ldv, bf16* __restrict__ vT)
{
    const int st = blockIdx.x, bh = blockIdx.y;
    const int b = bh >> 4, h = bh & 15;
    const int tid = threadIdx.x;
    __shared__ bf16 T[64 * 64];
#pragma unroll
    for (int i = 0; i < 2; ++i) {
        int idx = tid + 256 * i;
        int s = idx >> 3, ch = idx & 7;
        bf16x8 v = *reinterpret_cast<const bf16x8*>(
            vb + (size_t)(b * SS + st * 64 + s) * ldv + h * 64 + ch * 8);
        *reinterpret_cast<bf16x8*>((char*)T + swz(s, s * 128 + ch * 16)) = v;
    }
    __syncthreads();
#pragma unroll
    for (int i = 0; i < 2; ++i) {
        int idx = tid + 256 * i;
        int d = idx >> 3, ch = idx & 7;
        bf16x8 o;
#pragma unroll
        for (int j = 0; j < 8; ++j) {
            int s = ch * 8 + j;
            o[j] = *reinterpret_cast<const bf16*>((char*)T + swz(s, s * 128 + d * 2));
        }
        *reinterpret_cast<bf16x8*>(vT + ((size_t)bh * 64 + d) * SS + st * 64 + ch * 8) = o;
    }
}

// Flash attention: 8 waves x 32 q-rows, KVBLK=128, 16 iters, bias in LDS,
// fixed-shift softmax; kg-fused exp/pack/PV; l-reduction deferred to epilogue.
__global__ __launch_bounds__(512) void attn_kernel(
    const bf16* __restrict__ qkv, const bf16* __restrict__ vT,
    const float* __restrict__ bias, const int* __restrict__ mask,
    bf16* __restrict__ concat)
{
    const int w = blockIdx.x;                 // 0..511
    const int nw = (w & 7) * 64 + (w >> 3);
    const int qt = nw & 7, bh = nw >> 3;
    const int b = bh >> 4, h = bh & 15;
    const int tid = threadIdx.x;
    const int lane = tid & 63, wv = tid >> 6;
    const int lq = lane & 31, hi = lane >> 5;

    __shared__ bf16 Ks[2][128 * 64];
    __shared__ bf16 Vs[2][64 * 128];
    __shared__ float Bl[2048 + 16];

    const size_t tok0 = (size_t)b * SS;
    const int qrow0 = qt * 256 + wv * 32;

    const int qpad = mask[tok0 + qrow0 + lq];
    bf16x8 qf[4];
    {
        const bf16* qp = qkv + (tok0 + qrow0 + lq) * QKVLD + h * 64 + hi * 8;
#pragma unroll
        for (int ks = 0; ks < 4; ++ks) {
            bf16x8 v = *reinterpret_cast<const bf16x8*>(qp + ks * 16);
#pragma unroll
            for (int j = 0; j < 8; ++j)
                v[j] = qpad ? (bf16)0.f : (bf16)((float)v[j] * LOG2E_DIV8);
            qf[ks] = v;
        }
    }

    f32x16 oA, oB;
#pragma unroll
    for (int e = 0; e < 16; ++e) { oA[e] = 0.f; oB[e] = 0.f; }
    float ps[4] = {0.f, 0.f, 0.f, 0.f};   // persistent l partials (reduced once at end)

    const int c0 = tid, c1 = tid + 512;
    const int kr0 = c0 >> 3, kc0 = c0 & 7, kr1 = c1 >> 3, kc1 = c1 & 7;
    const int vr0 = c0 >> 4, vc0 = c0 & 15, vr1 = c1 >> 4, vc1 = c1 & 15;
    const char* kSrc = (const char*)(qkv + 1024 + h * 64);
    const char* vSrc = (const char*)(vT + (size_t)bh * 64 * SS);
    const size_t kOff0 = (tok0 + kr0) * (QKVLD * 2) + ((kc0 * 16) ^ ((kr0 & 7) << 4));
    const size_t kOff1 = (tok0 + kr1) * (QKVLD * 2) + ((kc1 * 16) ^ ((kr1 & 7) << 4));
    const size_t vOff0 = (size_t)vr0 * (SS * 2) + ((vc0 * 16) ^ ((vr0 & 15) << 4));
    const size_t vOff1 = (size_t)vr1 * (SS * 2) + ((vc1 * 16) ^ ((vr1 & 15) << 4));

    const int kxor = (hi * 16) ^ ((lq & 7) << 4);
    const int vxor = (hi * 16) ^ ((lq & 15) << 4);
    const int bmask = qpad ? 0 : -1;
    const char* bbase = (const char*)Bl + (qpad ? 8192 : hi * 64);

    gload_lds16(kSrc + kOff0, (char*)Ks[0] + c0 * 16);
    gload_lds16(kSrc + kOff1, (char*)Ks[0] + c1 * 16);
    gload_lds16(vSrc + vOff0, (char*)Vs[0] + c0 * 16);
    gload_lds16(vSrc + vOff1, (char*)Vs[0] + c1 * 16);
    gload_lds16((const char*)(bias + (size_t)b * 2048) + tid * 16, (char*)Bl + tid * 16);
    if (tid < 4) {
        f32x4 z = {-CSHIFT, -CSHIFT, -CSHIFT, -CSHIFT};
        *reinterpret_cast<f32x4*>((char*)Bl + 8192 + tid * 16) = z;
    }
    __syncthreads();

    for (int kt = 0; kt < 16; ++kt) {
        const int cur = kt & 1;

        if (kt < 15) {   // DMA next tile into other buffer; drained at end-of-iter sync
            const size_t kAdv = (size_t)(kt + 1) * 128 * (QKVLD * 2);
            const size_t vAdv = (size_t)(kt + 1) * 256;
            gload_lds16(kSrc + kOff0 + kAdv, (char*)Ks[cur ^ 1] + c0 * 16);
            gload_lds16(kSrc + kOff1 + kAdv, (char*)Ks[cur ^ 1] + c1 * 16);
            gload_lds16(vSrc + vOff0 + vAdv, (char*)Vs[cur ^ 1] + c0 * 16);
            gload_lds16(vSrc + vOff1 + vAdv, (char*)Vs[cur ^ 1] + c1 * 16);
        }

        const char* kB = (const char*)Ks[cur];
        const char* vB = (const char*)Vs[cur];
        const int bo = (kt * 512) & bmask;

        // QK^T: S^T[128 key][32 q], C-init = bias-with-shift from LDS
        f32x16 s[4];
#pragma unroll
        for (int kg = 0; kg < 4; ++kg)
            s[kg] = *reinterpret_cast<const f32x16*>(bbase + bo + ((kg * 128) & bmask));
        __builtin_amdgcn_s_setprio(1);
#pragma unroll
        for (int kg = 0; kg < 4; ++kg) {
            const char* kR = kB + (kg * 32 + lq) * 128;
#pragma unroll
            for (int ks = 0; ks < 4; ++ks) {
                bf16x8 kf = *reinterpret_cast<const bf16x8*>(kR + (kxor ^ (ks * 32)));
                s[kg] = __builtin_amdgcn_mfma_f32_32x32x16_bf16(kf, qf[ks], s[kg], 0, 0, 0);
            }
        }
        __builtin_amdgcn_s_setprio(0);

        // fused per-kg: exp(s[kg]) -> pack 2 fragments -> 4 PV MFMAs.
        // exp(s[kg+1]) is independent of PV(kg) -> scheduler can overlap pipes.
#pragma unroll
        for (int kg = 0; kg < 4; ++kg) {
#pragma unroll
            for (int e = 0; e < 16; ++e) {
                float t = fexp2(s[kg][e]);
                s[kg][e] = t;
                ps[e & 3] += t;
            }
            const float* pp = (const float*)&s[kg];
#pragma unroll
            for (int f = 0; f < 2; ++f) {
                const int kk = kg * 2 + f;
                uint32_t c0p = cvtpk(pp[8 * f + 0], pp[8 * f + 1]);
                uint32_t c1p = cvtpk(pp[8 * f + 2], pp[8 * f + 3]);
                uint32_t c2p = cvtpk(pp[8 * f + 4], pp[8 * f + 5]);
                uint32_t c3p = cvtpk(pp[8 * f + 6], pp[8 * f + 7]);
                asm("v_permlane32_swap_b32 %0, %1" : "+v"(c0p), "+v"(c2p));
                asm("v_permlane32_swap_b32 %0, %1" : "+v"(c1p), "+v"(c3p));
                union { uint32_t u[4]; bf16x8 v; } pu;
                pu.u[0] = c0p; pu.u[1] = c1p; pu.u[2] = c2p; pu.u[3] = c3p;
                bf16x8 vf0 = *reinterpret_cast<const bf16x8*>(
                    vB + (lq)*256 + (vxor ^ (kk * 32)));
                bf16x8 vf1 = *reinterpret_cast<const bf16x8*>(
                    vB + (32 + lq) * 256 + (vxor ^ (kk * 32)));
                oA = __builtin_amdgcn_mfma_f32_32x32x16_bf16(vf0, pu.v, oA, 0, 0, 0);
                oB = __builtin_amdgcn_mfma_f32_32x32x16_bf16(vf1, pu.v, oB, 0, 0, 0);
            }
        }

        if (kt < 15) __syncthreads();
    }

    // epilogue: single deferred l-reduction (shfl_xor is linear over the sum)
    float lsum = (ps[0] + ps[1]) + (ps[2] + ps[3]);
    lsum += __shfl_xor(lsum, 32);
    float inv = 1.0f / lsum;
#pragma unroll
    for (int g = 0; g < 4; ++g) {
        bf16x4 w0, w1;
#pragma unroll
        for (int r = 0; r < 4; ++r) {
            w0[r] = (bf16)(oA[g * 4 + r] * inv);
            w1[r] = (bf16)(oB[g * 4 + r] * inv);
        }
        int d0 = 4 * hi + 8 * g;
        bf16* cp = concat + (tok0 + qrow0 + lq) * QKVLD + h * 64 + d0;
        *reinterpret_cast<bf16x4*>(cp) = w0;
        *reinterpret_cast<bf16x4*>(cp + 32) = w1;
    }
}

extern "C" void kernel_launch(void* const* d_in, const int* in_sizes, int n_in,
                              void* d_out, int out_size, void* d_ws, size_t ws_size,
                              hipStream_t stream)
{
    const float* x  = (const float*)d_in[0];
    const int* mask = (const int*)d_in[1];
    const float* Wq = (const float*)d_in[2];
    const float* Wk = (const float*)d_in[3];
    const float* Wv = (const float*)d_in[4];
    const float* Wo = (const float*)d_in[5];
    float* out = (float*)d_out;

    // workspace (72 MiB):
    //  [0,16)  xb -> vT (xb dead after QKV gemm)
    //  [16,22) wqkv -> bias (dead after QKV gemm)   [22,24) wob
    //  [24,72) qkv [8192][3072]; v-cols (2048..3071) become concat after vtrans
    char* ws = (char*)d_ws;
    bf16* xb    = (bf16*)(ws);
    bf16* wqkv  = (bf16*)(ws + (16ull << 20));
    bf16* wob   = (bf16*)(ws + (22ull << 20));
    bf16* qkv   = (bf16*)(ws + (24ull << 20));
    bf16* vT    = xb;
    float* bias = (float*)wqkv;
    bf16* concat = qkv + 2048;   // strided [8192][.] within qkv, stride 3072

    cvt_kernel<<<dim3((NTOK * DM / 8) / 256), 256, 0, stream>>>(x, xb, NTOK * DM / 8);
    wcvt_kernel<<<dim3(2048), 256, 0, stream>>>(Wq, Wk, Wv, Wo, wqkv, wob);

    gemm_bt<bf16><<<dim3(QKVLD / 128, NTOK / 128), 256, 0, stream>>>(
        xb, DM, wqkv, qkv, NTOK, QKVLD, DM);

    vtrans_kernel<<<dim3(SS / 64, BB * NH), 256, 0, stream>>>(qkv + 2048, QKVLD, vT);
    biasprep_kernel<<<dim3(32), 256, 0, stream>>>(mask, bias);

    attn_kernel<<<dim3((SS / 256) * (BB * NH)), 512, 0, stream>>>(
        qkv, vT, bias, mask, concat);

    gemm_bt<float><<<dim3(DM / 128, NTOK / 128), 256, 0, stream>>>(
        concat, QKVLD, wob, out, NTOK, DM, DM);
}

// Round 14
// 188.242 us; speedup vs baseline: 1.1136x; 1.0063x over previous
//
#include <hip/hip_runtime.h>
#include <stdint.h>

// MultiHeadAttention: B=4, S=2048, D_MODEL=1024, H=16, d_k=d_v=64
// Round 14: (a) attn pipe rebalance — psum moved BACK to the matrix pipe
// (lacc ones-MFMA, r8's green path) since r9/r10 proved MFMA has slack
// (removing lacc was wall-neutral) while VALU is the fullest pipe (38%).
// (b) cvt_x + wcvt fused into one prep kernel. Rest = round 13.

typedef __bf16 bf16;
typedef __bf16 bf16x8 __attribute__((ext_vector_type(8)));
typedef __bf16 bf16x4 __attribute__((ext_vector_type(4)));
typedef float f32x4 __attribute__((ext_vector_type(4)));
typedef float f32x16 __attribute__((ext_vector_type(16)));

#define DM    1024
#define NH    16
#define SS    2048
#define BB    4
#define NTOK  8192
#define QKVLD 3072
#define XN8   (NTOK * DM / 8)             // 1048576 x-convert groups
#define LOG2E_DIV8 0.18033688011112042f   // log2(e)/8: scale folded into Q, exp2 domain
#define CSHIFT 12.0f                      // fixed softmax shift (folded into bias)

__device__ __forceinline__ int swz(int row, int byteoff) {
    return byteoff ^ ((row & 7) << 4);
}
__device__ __forceinline__ float fexp2(float x) {
    float r; asm("v_exp_f32 %0, %1" : "=v"(r) : "v"(x)); return r;
}
__device__ __forceinline__ uint32_t cvtpk(float lo, float hi_) {
    uint32_t r; asm("v_cvt_pk_bf16_f32 %0, %1, %2" : "=v"(r) : "v"(lo), "v"(hi_)); return r;
}
__device__ __forceinline__ void gload_lds16(const void* g, void* l) {
    __builtin_amdgcn_global_load_lds(
        (const __attribute__((address_space(1))) uint32_t*)g,
        (__attribute__((address_space(3))) uint32_t*)l, 16, 0, 0);
}

// fused fp32->bf16 convert: x (1M groups) + Wq/Wk/Wv (into wqkv) + Wo (wob)
__global__ void prep_kernel(const float* __restrict__ x,
                            const float* __restrict__ wq, const float* __restrict__ wk,
                            const float* __restrict__ wv, const float* __restrict__ wo,
                            bf16* __restrict__ xb, bf16* __restrict__ wqkv,
                            bf16* __restrict__ wob) {
    int i = blockIdx.x * blockDim.x + threadIdx.x;
    const float* src;
    bf16* dst;
    int off;
    if (i < XN8) {
        src = x; dst = xb; off = i;
    } else {
        int j = i - XN8;
        int seg = j >> 17;
        off = j & 131071;
        src = (seg == 0) ? wq : (seg == 1) ? wk : (seg == 2) ? wv : wo;
        dst = (seg < 3) ? (wqkv + (size_t)seg * DM * DM) : wob;
    }
    const float4* p = reinterpret_cast<const float4*>(src) + (size_t)off * 2;
    float4 a = p[0], b = p[1];
    bf16x8 o;
    o[0] = (bf16)a.x; o[1] = (bf16)a.y; o[2] = (bf16)a.z; o[3] = (bf16)a.w;
    o[4] = (bf16)b.x; o[5] = (bf16)b.y; o[6] = (bf16)b.z; o[7] = (bf16)b.w;
    reinterpret_cast<bf16x8*>(dst)[off] = o;
}

// bias[b4][kt16][kg4][hi2][e16]: -inf where key padded, else -CSHIFT.
__global__ void biasprep_kernel(const int* __restrict__ mask, float* __restrict__ bias) {
    int idx = blockIdx.x * blockDim.x + threadIdx.x;
    if (idx >= 4 * 2048) return;
    int e = idx & 15, hi = (idx >> 4) & 1, kg = (idx >> 5) & 3;
    int kt = (idx >> 7) & 15, b = idx >> 11;
    int key = kt * 128 + kg * 32 + 4 * hi + 8 * (e >> 2) + (e & 3);
    bias[idx] = mask[b * SS + key] ? -__builtin_inff() : -CSHIFT;
}

// C[M,N] = A[M,K](lda) * Bm[N,K]^T. 128x128 tile, BK=64, 4 waves, 16x16x32 MFMA.
template <typename OT>
__global__ __launch_bounds__(256) void gemm_bt(
    const bf16* __restrict__ A, int lda, const bf16* __restrict__ Bm, OT* __restrict__ C,
    int M, int N, int K)
{
    __shared__ bf16 As[128 * 64];
    __shared__ bf16 Bs[128 * 64];

    const int nwg = gridDim.x * gridDim.y;
    const int wg = blockIdx.y * gridDim.x + blockIdx.x;
    const int nsw = (wg & 7) * (nwg >> 3) + (wg >> 3);
    const int tn = nsw % gridDim.x, tm = nsw / gridDim.x;

    const int tid = threadIdx.x;
    const int lane = tid & 63, wv = tid >> 6;
    const int wr = wv >> 1, wc = wv & 1;
    const int lr = lane & 15, lg = lane >> 4;

    const f32x4 zero = {0.f, 0.f, 0.f, 0.f};
    f32x4 acc[4][4];
#pragma unroll
    for (int mi = 0; mi < 4; ++mi)
#pragma unroll
        for (int ni = 0; ni < 4; ++ni) acc[mi][ni] = zero;

    const char* Abase = (const char*)(A + (size_t)(tm * 128) * lda);
    const char* Bbase = (const char*)(Bm + (size_t)(tn * 128) * K);

    for (int k0 = 0; k0 < K; k0 += 64) {
#pragma unroll
        for (int i = 0; i < 4; ++i) {
            int idx = tid + 256 * i;
            int row = idx >> 3, ch = idx & 7;
            int gcol = (ch * 16) ^ ((row & 7) << 4);
            gload_lds16(Abase + (size_t)row * (lda * 2) + k0 * 2 + gcol, (char*)As + idx * 16);
            gload_lds16(Bbase + (size_t)row * (K * 2) + k0 * 2 + gcol, (char*)Bs + idx * 16);
        }
        __syncthreads();

#pragma unroll
        for (int ks = 0; ks < 2; ++ks) {
            bf16x8 af[4], bfr[4];
#pragma unroll
            for (int mi = 0; mi < 4; ++mi) {
                int row = wr * 64 + mi * 16 + lr;
                af[mi] = *reinterpret_cast<const bf16x8*>(
                    (char*)As + swz(row, row * 128 + ks * 64 + lg * 16));
            }
#pragma unroll
            for (int ni = 0; ni < 4; ++ni) {
                int row = wc * 64 + ni * 16 + lr;
                bfr[ni] = *reinterpret_cast<const bf16x8*>(
                    (char*)Bs + swz(row, row * 128 + ks * 64 + lg * 16));
            }
#pragma unroll
            for (int mi = 0; mi < 4; ++mi)
#pragma unroll
                for (int ni = 0; ni < 4; ++ni)
                    acc[mi][ni] = __builtin_amdgcn_mfma_f32_16x16x32_bf16(
                        af[mi], bfr[ni], acc[mi][ni], 0, 0, 0);
        }
        __syncthreads();
    }

#pragma unroll
    for (int mi = 0; mi < 4; ++mi)
#pragma unroll
        for (int ni = 0; ni < 4; ++ni)
#pragma unroll
            for (int r = 0; r < 4; ++r) {
                int row = tm * 128 + wr * 64 + mi * 16 + lg * 4 + r;
                int col = tn * 128 + wc * 64 + ni * 16 + lr;
                C[(size_t)row * N + col] = (OT)acc[mi][ni][r];
            }
}

// Transpose V: vb[token][ldv] head-cols -> vT[(bh*64+d)][s]
__global__ __launch_bounds__(256) void vtrans_kernel(
    const bf16* __restrict__ vb, int ldv, bf16* __restrict__ vT)
{
    const int st = blockIdx.x, bh = blockIdx.y;
    const int b = bh >> 4, h = bh & 15;
    const int tid = threadIdx.x;
    __shared__ bf16 T[64 * 64];
#pragma unroll
    for (int i = 0; i < 2; ++i) {
        int idx = tid + 256 * i;
        int s = idx >> 3, ch = idx & 7;
        bf16x8 v = *reinterpret_cast<const bf16x8*>(
            vb + (size_t)(b * SS + st * 64 + s) * ldv + h * 64 + ch * 8);
        *reinterpret_cast<bf16x8*>((char*)T + swz(s, s * 128 + ch * 16)) = v;
    }
    __syncthreads();
#pragma unroll
    for (int i = 0; i < 2; ++i) {
        int idx = tid + 256 * i;
        int d = idx >> 3, ch = idx & 7;
        bf16x8 o;
#pragma unroll
        for (int j = 0; j < 8; ++j) {
            int s = ch * 8 + j;
            o[j] = *reinterpret_cast<const bf16*>((char*)T + swz(s, s * 128 + d * 2));
        }
        *reinterpret_cast<bf16x8*>(vT + ((size_t)bh * 64 + d) * SS + st * 64 + ch * 8) = o;
    }
}

// Flash attention: 8 waves x 32 q-rows, KVBLK=128, 16 iters, bias in LDS,
// fixed-shift softmax; kg-fused exp/pack/PV; row-sum on the matrix pipe (lacc).
__global__ __launch_bounds__(512) void attn_kernel(
    const bf16* __restrict__ qkv, const bf16* __restrict__ vT,
    const float* __restrict__ bias, const int* __restrict__ mask,
    bf16* __restrict__ concat)
{
    const int w = blockIdx.x;                 // 0..511
    const int nw = (w & 7) * 64 + (w >> 3);
    const int qt = nw & 7, bh = nw >> 3;
    const int b = bh >> 4, h = bh & 15;
    const int tid = threadIdx.x;
    const int lane = tid & 63, wv = tid >> 6;
    const int lq = lane & 31, hi = lane >> 5;

    __shared__ bf16 Ks[2][128 * 64];
    __shared__ bf16 Vs[2][64 * 128];
    __shared__ float Bl[2048 + 16];

    const size_t tok0 = (size_t)b * SS;
    const int qrow0 = qt * 256 + wv * 32;

    const int qpad = mask[tok0 + qrow0 + lq];
    bf16x8 qf[4];
    {
        const bf16* qp = qkv + (tok0 + qrow0 + lq) * QKVLD + h * 64 + hi * 8;
#pragma unroll
        for (int ks = 0; ks < 4; ++ks) {
            bf16x8 v = *reinterpret_cast<const bf16x8*>(qp + ks * 16);
#pragma unroll
            for (int j = 0; j < 8; ++j)
                v[j] = qpad ? (bf16)0.f : (bf16)((float)v[j] * LOG2E_DIV8);
            qf[ks] = v;
        }
    }
    bf16x8 ones;
#pragma unroll
    for (int j = 0; j < 8; ++j) ones[j] = (bf16)1.0f;

    f32x16 oA, oB, lacc;
#pragma unroll
    for (int e = 0; e < 16; ++e) { oA[e] = 0.f; oB[e] = 0.f; lacc[e] = 0.f; }

    const int c0 = tid, c1 = tid + 512;
    const int kr0 = c0 >> 3, kc0 = c0 & 7, kr1 = c1 >> 3, kc1 = c1 & 7;
    const int vr0 = c0 >> 4, vc0 = c0 & 15, vr1 = c1 >> 4, vc1 = c1 & 15;
    const char* kSrc = (const char*)(qkv + 1024 + h * 64);
    const char* vSrc = (const char*)(vT + (size_t)bh * 64 * SS);
    const size_t kOff0 = (tok0 + kr0) * (QKVLD * 2) + ((kc0 * 16) ^ ((kr0 & 7) << 4));
    const size_t kOff1 = (tok0 + kr1) * (QKVLD * 2) + ((kc1 * 16) ^ ((kr1 & 7) << 4));
    const size_t vOff0 = (size_t)vr0 * (SS * 2) + ((vc0 * 16) ^ ((vr0 & 15) << 4));
    const size_t vOff1 = (size_t)vr1 * (SS * 2) + ((vc1 * 16) ^ ((vr1 & 15) << 4));

    const int kxor = (hi * 16) ^ ((lq & 7) << 4);
    const int vxor = (hi * 16) ^ ((lq & 15) << 4);
    const int bmask = qpad ? 0 : -1;
    const char* bbase = (const char*)Bl + (qpad ? 8192 : hi * 64);

    gload_lds16(kSrc + kOff0, (char*)Ks[0] + c0 * 16);
    gload_lds16(kSrc + kOff1, (char*)Ks[0] + c1 * 16);
    gload_lds16(vSrc + vOff0, (char*)Vs[0] + c0 * 16);
    gload_lds16(vSrc + vOff1, (char*)Vs[0] + c1 * 16);
    gload_lds16((const char*)(bias + (size_t)b * 2048) + tid * 16, (char*)Bl + tid * 16);
    if (tid < 4) {
        f32x4 z = {-CSHIFT, -CSHIFT, -CSHIFT, -CSHIFT};
        *reinterpret_cast<f32x4*>((char*)Bl + 8192 + tid * 16) = z;
    }
    __syncthreads();

    for (int kt = 0; kt < 16; ++kt) {
        const int cur = kt & 1;

        if (kt < 15) {   // DMA next tile into other buffer; drained at end-of-iter sync
            const size_t kAdv = (size_t)(kt + 1) * 128 * (QKVLD * 2);
            const size_t vAdv = (size_t)(kt + 1) * 256;
            gload_lds16(kSrc + kOff0 + kAdv, (char*)Ks[cur ^ 1] + c0 * 16);
            gload_lds16(kSrc + kOff1 + kAdv, (char*)Ks[cur ^ 1] + c1 * 16);
            gload_lds16(vSrc + vOff0 + vAdv, (char*)Vs[cur ^ 1] + c0 * 16);
            gload_lds16(vSrc + vOff1 + vAdv, (char*)Vs[cur ^ 1] + c1 * 16);
        }

        const char* kB = (const char*)Ks[cur];
        const char* vB = (const char*)Vs[cur];
        const int bo = (kt * 512) & bmask;

        // QK^T: S^T[128 key][32 q], C-init = bias-with-shift from LDS
        f32x16 s[4];
#pragma unroll
        for (int kg = 0; kg < 4; ++kg)
            s[kg] = *reinterpret_cast<const f32x16*>(bbase + bo + ((kg * 128) & bmask));
        __builtin_amdgcn_s_setprio(1);
#pragma unroll
        for (int kg = 0; kg < 4; ++kg) {
            const char* kR = kB + (kg * 32 + lq) * 128;
#pragma unroll
            for (int ks = 0; ks < 4; ++ks) {
                bf16x8 kf = *reinterpret_cast<const bf16x8*>(kR + (kxor ^ (ks * 32)));
                s[kg] = __builtin_amdgcn_mfma_f32_32x32x16_bf16(kf, qf[ks], s[kg], 0, 0, 0);
            }
        }
        __builtin_amdgcn_s_setprio(0);

        // fused per-kg: exp(s[kg]) -> pack 2 fragments -> 4 PV + 2 lacc MFMAs.
        // psum rides the matrix pipe (lacc); exp loop is pure v_exp.
#pragma unroll
        for (int kg = 0; kg < 4; ++kg) {
#pragma unroll
            for (int e = 0; e < 16; ++e)
                s[kg][e] = fexp2(s[kg][e]);
            const float* pp = (const float*)&s[kg];
#pragma unroll
            for (int f = 0; f < 2; ++f) {
                const int kk = kg * 2 + f;
                uint32_t c0p = cvtpk(pp[8 * f + 0], pp[8 * f + 1]);
                uint32_t c1p = cvtpk(pp[8 * f + 2], pp[8 * f + 3]);
                uint32_t c2p = cvtpk(pp[8 * f + 4], pp[8 * f + 5]);
                uint32_t c3p = cvtpk(pp[8 * f + 6], pp[8 * f + 7]);
                asm("v_permlane32_swap_b32 %0, %1" : "+v"(c0p), "+v"(c2p));
                asm("v_permlane32_swap_b32 %0, %1" : "+v"(c1p), "+v"(c3p));
                union { uint32_t u[4]; bf16x8 v; } pu;
                pu.u[0] = c0p; pu.u[1] = c1p; pu.u[2] = c2p; pu.u[3] = c3p;
                bf16x8 vf0 = *reinterpret_cast<const bf16x8*>(
                    vB + (lq)*256 + (vxor ^ (kk * 32)));
                bf16x8 vf1 = *reinterpret_cast<const bf16x8*>(
                    vB + (32 + lq) * 256 + (vxor ^ (kk * 32)));
                oA = __builtin_amdgcn_mfma_f32_32x32x16_bf16(vf0, pu.v, oA, 0, 0, 0);
                oB = __builtin_amdgcn_mfma_f32_32x32x16_bf16(vf1, pu.v, oB, 0, 0, 0);
                lacc = __builtin_amdgcn_mfma_f32_32x32x16_bf16(ones, pu.v, lacc, 0, 0, 0);
            }
        }

        if (kt < 15) __syncthreads();
    }

    // epilogue: lacc rows all equal the full key-sum for q = lane&31
    float inv = 1.0f / lacc[0];
#pragma unroll
    for (int g = 0; g < 4; ++g) {
        bf16x4 w0, w1;
#pragma unroll
        for (int r = 0; r < 4; ++r) {
            w0[r] = (bf16)(oA[g * 4 + r] * inv);
            w1[r] = (bf16)(oB[g * 4 + r] * inv);
        }
        int d0 = 4 * hi + 8 * g;
        bf16* cp = concat + (tok0 + qrow0 + lq) * QKVLD + h * 64 + d0;
        *reinterpret_cast<bf16x4*>(cp) = w0;
        *reinterpret_cast<bf16x4*>(cp + 32) = w1;
    }
}

extern "C" void kernel_launch(void* const* d_in, const int* in_sizes, int n_in,
                              void* d_out, int out_size, void* d_ws, size_t ws_size,
                              hipStream_t stream)
{
    const float* x  = (const float*)d_in[0];
    const int* mask = (const int*)d_in[1];
    const float* Wq = (const float*)d_in[2];
    const float* Wk = (const float*)d_in[3];
    const float* Wv = (const float*)d_in[4];
    const float* Wo = (const float*)d_in[5];
    float* out = (float*)d_out;

    // workspace (72 MiB):
    //  [0,16)  xb -> vT (xb dead after QKV gemm)
    //  [16,22) wqkv -> bias (dead after QKV gemm)   [22,24) wob
    //  [24,72) qkv [8192][3072]; v-cols (2048..3071) become concat after vtrans
    char* ws = (char*)d_ws;
    bf16* xb    = (bf16*)(ws);
    bf16* wqkv  = (bf16*)(ws + (16ull << 20));
    bf16* wob   = (bf16*)(ws + (22ull << 20));
    bf16* qkv   = (bf16*)(ws + (24ull << 20));
    bf16* vT    = xb;
    float* bias = (float*)wqkv;
    bf16* concat = qkv + 2048;   // strided [8192][.] within qkv, stride 3072

    // fused converts: x (4096 blocks) + 4 weight mats (2048 blocks)
    prep_kernel<<<dim3(6144), 256, 0, stream>>>(x, Wq, Wk, Wv, Wo, xb, wqkv, wob);

    gemm_bt<bf16><<<dim3(QKVLD / 128, NTOK / 128), 256, 0, stream>>>(
        xb, DM, wqkv, qkv, NTOK, QKVLD, DM);

    vtrans_kernel<<<dim3(SS / 64, BB * NH), 256, 0, stream>>>(qkv + 2048, QKVLD, vT);
    biasprep_kernel<<<dim3(32), 256, 0, stream>>>(mask, bias);

    attn_kernel<<<dim3((SS / 256) * (BB * NH)), 512, 0, stream>>>(
        qkv, vT, bias, mask, concat);

    gemm_bt<float><<<dim3(DM / 128, NTOK / 128), 256, 0, stream>>>(
        concat, QKVLD, wob, out, NTOK, DM, DM);
}

// Round 15
// 187.989 us; speedup vs baseline: 1.1151x; 1.0013x over previous
//
#include <hip/hip_runtime.h>
#include <stdint.h>

// MultiHeadAttention: B=4, S=2048, D_MODEL=1024, H=16, d_k=d_v=64
// Round 15: merge of the two best measured pieces — attn = round-13 exact
// (97.2 µs: kg-fused exp/pack/PV, VALU psum, deferred l-reduction; r14's
// lacc variant was 99.6) + round-14's fused prep convert kernel.

typedef __bf16 bf16;
typedef __bf16 bf16x8 __attribute__((ext_vector_type(8)));
typedef __bf16 bf16x4 __attribute__((ext_vector_type(4)));
typedef float f32x4 __attribute__((ext_vector_type(4)));
typedef float f32x16 __attribute__((ext_vector_type(16)));

#define DM    1024
#define NH    16
#define SS    2048
#define BB    4
#define NTOK  8192
#define QKVLD 3072
#define XN8   (NTOK * DM / 8)             // 1048576 x-convert groups
#define LOG2E_DIV8 0.18033688011112042f   // log2(e)/8: scale folded into Q, exp2 domain
#define CSHIFT 12.0f                      // fixed softmax shift (folded into bias)

__device__ __forceinline__ int swz(int row, int byteoff) {
    return byteoff ^ ((row & 7) << 4);
}
__device__ __forceinline__ float fexp2(float x) {
    float r; asm("v_exp_f32 %0, %1" : "=v"(r) : "v"(x)); return r;
}
__device__ __forceinline__ uint32_t cvtpk(float lo, float hi_) {
    uint32_t r; asm("v_cvt_pk_bf16_f32 %0, %1, %2" : "=v"(r) : "v"(lo), "v"(hi_)); return r;
}
__device__ __forceinline__ void gload_lds16(const void* g, void* l) {
    __builtin_amdgcn_global_load_lds(
        (const __attribute__((address_space(1))) uint32_t*)g,
        (__attribute__((address_space(3))) uint32_t*)l, 16, 0, 0);
}

// fused fp32->bf16 convert: x (1M groups) + Wq/Wk/Wv (into wqkv) + Wo (wob)
__global__ void prep_kernel(const float* __restrict__ x,
                            const float* __restrict__ wq, const float* __restrict__ wk,
                            const float* __restrict__ wv, const float* __restrict__ wo,
                            bf16* __restrict__ xb, bf16* __restrict__ wqkv,
                            bf16* __restrict__ wob) {
    int i = blockIdx.x * blockDim.x + threadIdx.x;
    const float* src;
    bf16* dst;
    int off;
    if (i < XN8) {
        src = x; dst = xb; off = i;
    } else {
        int j = i - XN8;
        int seg = j >> 17;
        off = j & 131071;
        src = (seg == 0) ? wq : (seg == 1) ? wk : (seg == 2) ? wv : wo;
        dst = (seg < 3) ? (wqkv + (size_t)seg * DM * DM) : wob;
    }
    const float4* p = reinterpret_cast<const float4*>(src) + (size_t)off * 2;
    float4 a = p[0], b = p[1];
    bf16x8 o;
    o[0] = (bf16)a.x; o[1] = (bf16)a.y; o[2] = (bf16)a.z; o[3] = (bf16)a.w;
    o[4] = (bf16)b.x; o[5] = (bf16)b.y; o[6] = (bf16)b.z; o[7] = (bf16)b.w;
    reinterpret_cast<bf16x8*>(dst)[off] = o;
}

// bias[b4][kt16][kg4][hi2][e16]: -inf where key padded, else -CSHIFT.
__global__ void biasprep_kernel(const int* __restrict__ mask, float* __restrict__ bias) {
    int idx = blockIdx.x * blockDim.x + threadIdx.x;
    if (idx >= 4 * 2048) return;
    int e = idx & 15, hi = (idx >> 4) & 1, kg = (idx >> 5) & 3;
    int kt = (idx >> 7) & 15, b = idx >> 11;
    int key = kt * 128 + kg * 32 + 4 * hi + 8 * (e >> 2) + (e & 3);
    bias[idx] = mask[b * SS + key] ? -__builtin_inff() : -CSHIFT;
}

// C[M,N] = A[M,K](lda) * Bm[N,K]^T. 128x128 tile, BK=64, 4 waves, 16x16x32 MFMA.
template <typename OT>
__global__ __launch_bounds__(256) void gemm_bt(
    const bf16* __restrict__ A, int lda, const bf16* __restrict__ Bm, OT* __restrict__ C,
    int M, int N, int K)
{
    __shared__ bf16 As[128 * 64];
    __shared__ bf16 Bs[128 * 64];

    const int nwg = gridDim.x * gridDim.y;
    const int wg = blockIdx.y * gridDim.x + blockIdx.x;
    const int nsw = (wg & 7) * (nwg >> 3) + (wg >> 3);
    const int tn = nsw % gridDim.x, tm = nsw / gridDim.x;

    const int tid = threadIdx.x;
    const int lane = tid & 63, wv = tid >> 6;
    const int wr = wv >> 1, wc = wv & 1;
    const int lr = lane & 15, lg = lane >> 4;

    const f32x4 zero = {0.f, 0.f, 0.f, 0.f};
    f32x4 acc[4][4];
#pragma unroll
    for (int mi = 0; mi < 4; ++mi)
#pragma unroll
        for (int ni = 0; ni < 4; ++ni) acc[mi][ni] = zero;

    const char* Abase = (const char*)(A + (size_t)(tm * 128) * lda);
    const char* Bbase = (const char*)(Bm + (size_t)(tn * 128) * K);

    for (int k0 = 0; k0 < K; k0 += 64) {
#pragma unroll
        for (int i = 0; i < 4; ++i) {
            int idx = tid + 256 * i;
            int row = idx >> 3, ch = idx & 7;
            int gcol = (ch * 16) ^ ((row & 7) << 4);
            gload_lds16(Abase + (size_t)row * (lda * 2) + k0 * 2 + gcol, (char*)As + idx * 16);
            gload_lds16(Bbase + (size_t)row * (K * 2) + k0 * 2 + gcol, (char*)Bs + idx * 16);
        }
        __syncthreads();

#pragma unroll
        for (int ks = 0; ks < 2; ++ks) {
            bf16x8 af[4], bfr[4];
#pragma unroll
            for (int mi = 0; mi < 4; ++mi) {
                int row = wr * 64 + mi * 16 + lr;
                af[mi] = *reinterpret_cast<const bf16x8*>(
                    (char*)As + swz(row, row * 128 + ks * 64 + lg * 16));
            }
#pragma unroll
            for (int ni = 0; ni < 4; ++ni) {
                int row = wc * 64 + ni * 16 + lr;
                bfr[ni] = *reinterpret_cast<const bf16x8*>(
                    (char*)Bs + swz(row, row * 128 + ks * 64 + lg * 16));
            }
#pragma unroll
            for (int mi = 0; mi < 4; ++mi)
#pragma unroll
                for (int ni = 0; ni < 4; ++ni)
                    acc[mi][ni] = __builtin_amdgcn_mfma_f32_16x16x32_bf16(
                        af[mi], bfr[ni], acc[mi][ni], 0, 0, 0);
        }
        __syncthreads();
    }

#pragma unroll
    for (int mi = 0; mi < 4; ++mi)
#pragma unroll
        for (int ni = 0; ni < 4; ++ni)
#pragma unroll
            for (int r = 0; r < 4; ++r) {
                int row = tm * 128 + wr * 64 + mi * 16 + lg * 4 + r;
                int col = tn * 128 + wc * 64 + ni * 16 + lr;
                C[(size_t)row * N + col] = (OT)acc[mi][ni][r];
            }
}

// Transpose V: vb[token][ldv] head-cols -> vT[(bh*64+d)][s]
__global__ __launch_bounds__(256) void vtrans_kernel(
    const bf16* __restrict__ vb, int ldv, bf16* __restrict__ vT)
{
    const int st = blockIdx.x, bh = blockIdx.y;
    const int b = bh >> 4, h = bh & 15;
    const int tid = threadIdx.x;
    __shared__ bf16 T[64 * 64];
#pragma unroll
    for (int i = 0; i < 2; ++i) {
        int idx = tid + 256 * i;
        int s = idx >> 3, ch = idx & 7;
        bf16x8 v = *reinterpret_cast<const bf16x8*>(
            vb + (size_t)(b * SS + st * 64 + s) * ldv + h * 64 + ch * 8);
        *reinterpret_cast<bf16x8*>((char*)T + swz(s, s * 128 + ch * 16)) = v;
    }
    __syncthreads();
#pragma unroll
    for (int i = 0; i < 2; ++i) {
        int idx = tid + 256 * i;
        int d = idx >> 3, ch = idx & 7;
        bf16x8 o;
#pragma unroll
        for (int j = 0; j < 8; ++j) {
            int s = ch * 8 + j;
            o[j] = *reinterpret_cast<const bf16*>((char*)T + swz(s, s * 128 + d * 2));
        }
        *reinterpret_cast<bf16x8*>(vT + ((size_t)bh * 64 + d) * SS + st * 64 + ch * 8) = o;
    }
}

// Flash attention (round-13 exact): 8 waves x 32 q-rows, KVBLK=128, 16 iters,
// bias in LDS, fixed-shift softmax; kg-fused exp/pack/PV; deferred l-reduction.
__global__ __launch_bounds__(512) void attn_kernel(
    const bf16* __restrict__ qkv, const bf16* __restrict__ vT,
    const float* __restrict__ bias, const int* __restrict__ mask,
    bf16* __restrict__ concat)
{
    const int w = blockIdx.x;                 // 0..511
    const int nw = (w & 7) * 64 + (w >> 3);
    const int qt = nw & 7, bh = nw >> 3;
    const int b = bh >> 4, h = bh & 15;
    const int tid = threadIdx.x;
    const int lane = tid & 63, wv = tid >> 6;
    const int lq = lane & 31, hi = lane >> 5;

    __shared__ bf16 Ks[2][128 * 64];
    __shared__ bf16 Vs[2][64 * 128];
    __shared__ float Bl[2048 + 16];

    const size_t tok0 = (size_t)b * SS;
    const int qrow0 = qt * 256 + wv * 32;

    const int qpad = mask[tok0 + qrow0 + lq];
    bf16x8 qf[4];
    {
        const bf16* qp = qkv + (tok0 + qrow0 + lq) * QKVLD + h * 64 + hi * 8;
#pragma unroll
        for (int ks = 0; ks < 4; ++ks) {
            bf16x8 v = *reinterpret_cast<const bf16x8*>(qp + ks * 16);
#pragma unroll
            for (int j = 0; j < 8; ++j)
                v[j] = qpad ? (bf16)0.f : (bf16)((float)v[j] * LOG2E_DIV8);
            qf[ks] = v;
        }
    }

    f32x16 oA, oB;
#pragma unroll
    for (int e = 0; e < 16; ++e) { oA[e] = 0.f; oB[e] = 0.f; }
    float ps[4] = {0.f, 0.f, 0.f, 0.f};   // persistent l partials (reduced once at end)

    const int c0 = tid, c1 = tid + 512;
    const int kr0 = c0 >> 3, kc0 = c0 & 7, kr1 = c1 >> 3, kc1 = c1 & 7;
    const int vr0 = c0 >> 4, vc0 = c0 & 15, vr1 = c1 >> 4, vc1 = c1 & 15;
    const char* kSrc = (const char*)(qkv + 1024 + h * 64);
    const char* vSrc = (const char*)(vT + (size_t)bh * 64 * SS);
    const size_t kOff0 = (tok0 + kr0) * (QKVLD * 2) + ((kc0 * 16) ^ ((kr0 & 7) << 4));
    const size_t kOff1 = (tok0 + kr1) * (QKVLD * 2) + ((kc1 * 16) ^ ((kr1 & 7) << 4));
    const size_t vOff0 = (size_t)vr0 * (SS * 2) + ((vc0 * 16) ^ ((vr0 & 15) << 4));
    const size_t vOff1 = (size_t)vr1 * (SS * 2) + ((vc1 * 16) ^ ((vr1 & 15) << 4));

    const int kxor = (hi * 16) ^ ((lq & 7) << 4);
    const int vxor = (hi * 16) ^ ((lq & 15) << 4);
    const int bmask = qpad ? 0 : -1;
    const char* bbase = (const char*)Bl + (qpad ? 8192 : hi * 64);

    gload_lds16(kSrc + kOff0, (char*)Ks[0] + c0 * 16);
    gload_lds16(kSrc + kOff1, (char*)Ks[0] + c1 * 16);
    gload_lds16(vSrc + vOff0, (char*)Vs[0] + c0 * 16);
    gload_lds16(vSrc + vOff1, (char*)Vs[0] + c1 * 16);
    gload_lds16((const char*)(bias + (size_t)b * 2048) + tid * 16, (char*)Bl + tid * 16);
    if (tid < 4) {
        f32x4 z = {-CSHIFT, -CSHIFT, -CSHIFT, -CSHIFT};
        *reinterpret_cast<f32x4*>((char*)Bl + 8192 + tid * 16) = z;
    }
    __syncthreads();

    for (int kt = 0; kt < 16; ++kt) {
        const int cur = kt & 1;

        if (kt < 15) {   // DMA next tile into other buffer; drained at end-of-iter sync
            const size_t kAdv = (size_t)(kt + 1) * 128 * (QKVLD * 2);
            const size_t vAdv = (size_t)(kt + 1) * 256;
            gload_lds16(kSrc + kOff0 + kAdv, (char*)Ks[cur ^ 1] + c0 * 16);
            gload_lds16(kSrc + kOff1 + kAdv, (char*)Ks[cur ^ 1] + c1 * 16);
            gload_lds16(vSrc + vOff0 + vAdv, (char*)Vs[cur ^ 1] + c0 * 16);
            gload_lds16(vSrc + vOff1 + vAdv, (char*)Vs[cur ^ 1] + c1 * 16);
        }

        const char* kB = (const char*)Ks[cur];
        const char* vB = (const char*)Vs[cur];
        const int bo = (kt * 512) & bmask;

        // QK^T: S^T[128 key][32 q], C-init = bias-with-shift from LDS
        f32x16 s[4];
#pragma unroll
        for (int kg = 0; kg < 4; ++kg)
            s[kg] = *reinterpret_cast<const f32x16*>(bbase + bo + ((kg * 128) & bmask));
        __builtin_amdgcn_s_setprio(1);
#pragma unroll
        for (int kg = 0; kg < 4; ++kg) {
            const char* kR = kB + (kg * 32 + lq) * 128;
#pragma unroll
            for (int ks = 0; ks < 4; ++ks) {
                bf16x8 kf = *reinterpret_cast<const bf16x8*>(kR + (kxor ^ (ks * 32)));
                s[kg] = __builtin_amdgcn_mfma_f32_32x32x16_bf16(kf, qf[ks], s[kg], 0, 0, 0);
            }
        }
        __builtin_amdgcn_s_setprio(0);

        // fused per-kg: exp(s[kg]) -> pack 2 fragments -> 4 PV MFMAs.
#pragma unroll
        for (int kg = 0; kg < 4; ++kg) {
#pragma unroll
            for (int e = 0; e < 16; ++e) {
                float t = fexp2(s[kg][e]);
                s[kg][e] = t;
                ps[e & 3] += t;
            }
            const float* pp = (const float*)&s[kg];
#pragma unroll
            for (int f = 0; f < 2; ++f) {
                const int kk = kg * 2 + f;
                uint32_t c0p = cvtpk(pp[8 * f + 0], pp[8 * f + 1]);
                uint32_t c1p = cvtpk(pp[8 * f + 2], pp[8 * f + 3]);
                uint32_t c2p = cvtpk(pp[8 * f + 4], pp[8 * f + 5]);
                uint32_t c3p = cvtpk(pp[8 * f + 6], pp[8 * f + 7]);
                asm("v_permlane32_swap_b32 %0, %1" : "+v"(c0p), "+v"(c2p));
                asm("v_permlane32_swap_b32 %0, %1" : "+v"(c1p), "+v"(c3p));
                union { uint32_t u[4]; bf16x8 v; } pu;
                pu.u[0] = c0p; pu.u[1] = c1p; pu.u[2] = c2p; pu.u[3] = c3p;
                bf16x8 vf0 = *reinterpret_cast<const bf16x8*>(
                    vB + (lq)*256 + (vxor ^ (kk * 32)));
                bf16x8 vf1 = *reinterpret_cast<const bf16x8*>(
                    vB + (32 + lq) * 256 + (vxor ^ (kk * 32)));
                oA = __builtin_amdgcn_mfma_f32_32x32x16_bf16(vf0, pu.v, oA, 0, 0, 0);
                oB = __builtin_amdgcn_mfma_f32_32x32x16_bf16(vf1, pu.v, oB, 0, 0, 0);
            }
        }

        if (kt < 15) __syncthreads();
    }

    // epilogue: single deferred l-reduction (shfl_xor is linear over the sum)
    float lsum = (ps[0] + ps[1]) + (ps[2] + ps[3]);
    lsum += __shfl_xor(lsum, 32);
    float inv = 1.0f / lsum;
#pragma unroll
    for (int g = 0; g < 4; ++g) {
        bf16x4 w0, w1;
#pragma unroll
        for (int r = 0; r < 4; ++r) {
            w0[r] = (bf16)(oA[g * 4 + r] * inv);
            w1[r] = (bf16)(oB[g * 4 + r] * inv);
        }
        int d0 = 4 * hi + 8 * g;
        bf16* cp = concat + (tok0 + qrow0 + lq) * QKVLD + h * 64 + d0;
        *reinterpret_cast<bf16x4*>(cp) = w0;
        *reinterpret_cast<bf16x4*>(cp + 32) = w1;
    }
}

extern "C" void kernel_launch(void* const* d_in, const int* in_sizes, int n_in,
                              void* d_out, int out_size, void* d_ws, size_t ws_size,
                              hipStream_t stream)
{
    const float* x  = (const float*)d_in[0];
    const int* mask = (const int*)d_in[1];
    const float* Wq = (const float*)d_in[2];
    const float* Wk = (const float*)d_in[3];
    const float* Wv = (const float*)d_in[4];
    const float* Wo = (const float*)d_in[5];
    float* out = (float*)d_out;

    // workspace (72 MiB):
    //  [0,16)  xb -> vT (xb dead after QKV gemm)
    //  [16,22) wqkv -> bias (dead after QKV gemm)   [22,24) wob
    //  [24,72) qkv [8192][3072]; v-cols (2048..3071) become concat after vtrans
    char* ws = (char*)d_ws;
    bf16* xb    = (bf16*)(ws);
    bf16* wqkv  = (bf16*)(ws + (16ull << 20));
    bf16* wob   = (bf16*)(ws + (22ull << 20));
    bf16* qkv   = (bf16*)(ws + (24ull << 20));
    bf16* vT    = xb;
    float* bias = (float*)wqkv;
    bf16* concat = qkv + 2048;   // strided [8192][.] within qkv, stride 3072

    // fused converts: x (4096 blocks) + 4 weight mats (2048 blocks)
    prep_kernel<<<dim3(6144), 256, 0, stream>>>(x, Wq, Wk, Wv, Wo, xb, wqkv, wob);

    gemm_bt<bf16><<<dim3(QKVLD / 128, NTOK / 128), 256, 0, stream>>>(
        xb, DM, wqkv, qkv, NTOK, QKVLD, DM);

    vtrans_kernel<<<dim3(SS / 64, BB * NH), 256, 0, stream>>>(qkv + 2048, QKVLD, vT);
    biasprep_kernel<<<dim3(32), 256, 0, stream>>>(mask, bias);

    attn_kernel<<<dim3((SS / 256) * (BB * NH)), 512, 0, stream>>>(
        qkv, vT, bias, mask, concat);

    gemm_bt<float><<<dim3(DM / 128, NTOK / 128), 256, 0, stream>>>(
        concat, QKVLD, wob, out, NTOK, DM, DM);
}